// Round 13
// baseline (1471.090 us; speedup 1.0000x reference)
//
#include <hip/hip_runtime.h>
#include <math.h>

// ---------------- problem constants ----------------
#define BBATCH 4
#define SS 512
#define DDIM 512
#define FFN 2048
#define NHEAD 8
#define DHEAD 64
#define NL 6
#define NVOC 32000
#define MTOK (BBATCH*SS)       // 2048
#define PAD_ID 0
#define MSZE ((size_t)MTOK * DDIM)   // 1,048,576 elements

typedef unsigned short u16;
typedef __attribute__((ext_vector_type(8))) short short8;   // 8 bf16 (4 VGPRs)
typedef __attribute__((ext_vector_type(4))) float f32x4;

__device__ __forceinline__ u16 f2bf(float f) {
    union { float f; unsigned u; } v; v.f = f;
    unsigned r = ((v.u >> 16) & 1u) + 0x7fffu;   // round-to-nearest-even
    return (u16)((v.u + r) >> 16);
}

__device__ __forceinline__ void gload16(const u16* g, u16* l) {
    __builtin_amdgcn_global_load_lds(
        (const __attribute__((address_space(1))) void*)g,
        (__attribute__((address_space(3))) void*)l, 16, 0, 0);
}

// counted vmcnt wait (literal-immediate) + scheduling fence (rule #18)
template<int N> __device__ __forceinline__ void waitv() {
    if constexpr (N == 0)       asm volatile("s_waitcnt vmcnt(0)" ::: "memory");
    else if constexpr (N == 2)  asm volatile("s_waitcnt vmcnt(2)" ::: "memory");
    else if constexpr (N == 4)  asm volatile("s_waitcnt vmcnt(4)" ::: "memory");
    else if constexpr (N == 6)  asm volatile("s_waitcnt vmcnt(6)" ::: "memory");
    else if constexpr (N == 8)  asm volatile("s_waitcnt vmcnt(8)" ::: "memory");
    else if constexpr (N == 12) asm volatile("s_waitcnt vmcnt(12)" ::: "memory");
    __builtin_amdgcn_sched_barrier(0);
}
__device__ __forceinline__ void rawbar() {
    __builtin_amdgcn_s_barrier();
    __builtin_amdgcn_sched_barrier(0);
}

// ======================= MFMA GEMM core (NT): C[M,N] = A[M,K] * B[N,K]^T =======================
// 4-slot LDS ring, 3 tiles in flight (counted vmcnt). 256 threads = 4 waves (2x2).
template<int BM, int BN, int OUTBF, int RELU, int BIAS>
__device__ __forceinline__ void gemm_core(
    u16* __restrict__ AsB, u16* __restrict__ BsB,     // 4*BM*32 / 4*BN*32
    const u16* __restrict__ A, int lda,
    const u16* __restrict__ B, int ldb,
    void* __restrict__ Cv, int ldc,
    int row0, int col0, int K, const float* __restrict__ bias)
{
    const int tid  = threadIdx.x;
    const int lane = tid & 63;
    const int wid  = tid >> 6;
    const int wr   = wid >> 1, wc = wid & 1;
    constexpr int MF = BM / 32, NF = BN / 32, RA = BM / 64, RB = BN / 64;
    constexpr int LPT = RA + RB;

    const u16* aSrc[RA]; int aOff[RA];
    #pragma unroll
    for (int r = 0; r < RA; r++) {
        int row = (tid >> 2) + r * 64;
        int slot = ((tid & 3) << 4) ^ ((row & 3) << 4);
        aSrc[r] = A + (size_t)(row0 + row) * lda + (slot >> 1);
        aOff[r] = r * 2048 + tid * 8;
    }
    const u16* bSrc[RB]; int bOff[RB];
    #pragma unroll
    for (int r = 0; r < RB; r++) {
        int row = (tid >> 2) + r * 64;
        int slot = ((tid & 3) << 4) ^ ((row & 3) << 4);
        bSrc[r] = B + (size_t)(col0 + row) * ldb + (slot >> 1);
        bOff[r] = r * 2048 + tid * 8;
    }

    f32x4 acc[MF][NF];
    const f32x4 zero = {0.f, 0.f, 0.f, 0.f};
    #pragma unroll
    for (int m = 0; m < MF; m++)
        #pragma unroll
        for (int n = 0; n < NF; n++) acc[m][n] = zero;

    auto issue = [&](int t) {
        u16* ad = AsB + (t & 3) * (BM * 32);
        u16* bd = BsB + (t & 3) * (BN * 32);
        #pragma unroll
        for (int r = 0; r < RA; r++) gload16(aSrc[r] + t * 32, ad + aOff[r]);
        #pragma unroll
        for (int r = 0; r < RB; r++) gload16(bSrc[r] + t * 32, bd + bOff[r]);
    };
    auto comp = [&](int t) {
        const u16* as = AsB + (t & 3) * (BM * 32);
        const u16* bs = BsB + (t & 3) * (BN * 32);
        short8 af[MF], bf[NF];
        #pragma unroll
        for (int m = 0; m < MF; m++) {
            int row = wr * (BM / 2) + m * 16 + (lane & 15);
            int slot = ((lane >> 4) << 4) ^ ((row & 3) << 4);
            af[m] = *(const short8*)&as[row * 32 + (slot >> 1)];
        }
        #pragma unroll
        for (int n = 0; n < NF; n++) {
            int row = wc * (BN / 2) + n * 16 + (lane & 15);
            int slot = ((lane >> 4) << 4) ^ ((row & 3) << 4);
            bf[n] = *(const short8*)&bs[row * 32 + (slot >> 1)];
        }
        __builtin_amdgcn_s_setprio(1);
        #pragma unroll
        for (int m = 0; m < MF; m++)
            #pragma unroll
            for (int n = 0; n < NF; n++)
                acc[m][n] = __builtin_amdgcn_mfma_f32_16x16x32_bf16(af[m], bf[n], acc[m][n], 0, 0, 0);
        __builtin_amdgcn_s_setprio(0);
    };

    const int nt = K / 32;
    issue(0); issue(1); issue(2);
    int t = 0;
    for (; t < nt - 2; ++t) {
        waitv<2 * LPT>();
        rawbar();
        if (t + 3 < nt) issue(t + 3);
        comp(t);
    }
    waitv<LPT>(); rawbar(); comp(nt - 2);
    waitv<0>();   rawbar(); comp(nt - 1);

    const int crow = row0 + wr * (BM / 2);
    const int ccol = col0 + wc * (BN / 2);
    #pragma unroll
    for (int m = 0; m < MF; m++) {
        #pragma unroll
        for (int n = 0; n < NF; n++) {
            int col = ccol + n * 16 + (lane & 15);
            float bv = BIAS ? bias[col] : 0.0f;
            #pragma unroll
            for (int i = 0; i < 4; i++) {
                int row = crow + m * 16 + ((lane >> 4) << 2) + i;
                float v = acc[m][n][i] + bv;
                if (RELU) v = fmaxf(v, 0.0f);
                if (OUTBF) ((u16*)Cv)[(size_t)row * ldc + col] = f2bf(v);
                else       ((float*)Cv)[(size_t)row * ldc + col] = v;
            }
        }
    }
}

// batched/swizzled wrapper (z: zb = z>>3 batch stride, zh = z&7 head/split stride)
template<int BM, int BN, int OUTBF, int RELU, int BIAS, int SWZ = 0>
__global__ __launch_bounds__(256) void mgemm(
    const u16* __restrict__ A, int lda, size_t aSb, size_t aSh,
    const u16* __restrict__ B, int ldb, size_t bSb, size_t bSh,
    void* __restrict__ Cv, int ldc, size_t cSb, size_t cSh,
    int K, const float* __restrict__ bias)
{
    __shared__ __align__(16) u16 As[4 * BM * 32];
    __shared__ __align__(16) u16 Bs[4 * BN * 32];
    int bx = blockIdx.x, by = blockIdx.y;
    if (SWZ) {
        int nwg = gridDim.x * gridDim.y;
        int lin = by * gridDim.x + bx;
        int cpx = nwg >> 3;
        int s = (lin & 7) * cpx + (lin >> 3);
        bx = s % gridDim.x; by = s / gridDim.x;
    }
    const int zb = blockIdx.z >> 3, zh = blockIdx.z & 7;
    const u16* Ab = A + (size_t)zb * aSb + (size_t)zh * aSh;
    const u16* Bb = B + (size_t)zb * bSb + (size_t)zh * bSh;
    void* Cb = OUTBF ? (void*)((u16*)Cv + (size_t)zb * cSb + (size_t)zh * cSh)
                     : (void*)((float*)Cv + (size_t)zb * cSb + (size_t)zh * cSh);
    gemm_core<BM, BN, OUTBF, RELU, BIAS>(As, Bs, Ab, lda, Bb, ldb, Cb, ldc,
                                          by * BM, bx * BN, K, bias);
}

// dual-job GEMM: two independent NT gemms in one launch (bf16 out, no bias)
template<int BM, int BN>
__global__ __launch_bounds__(256) void mgemm_dual(
    const u16* __restrict__ A1, int lda1, const u16* __restrict__ B1, int ldb1,
    u16* __restrict__ C1, int ldc1, int nx1, int nblk1,
    const u16* __restrict__ A2, int lda2, const u16* __restrict__ B2, int ldb2,
    u16* __restrict__ C2, int ldc2, int nx2,
    int K)
{
    __shared__ __align__(16) u16 As[4 * BM * 32];
    __shared__ __align__(16) u16 Bs[4 * BN * 32];
    int id = blockIdx.x;
    if (id < nblk1) {
        gemm_core<BM, BN, 1, 0, 0>(As, Bs, A1, lda1, B1, ldb1, C1, ldc1,
                                    (id / nx1) * BM, (id % nx1) * BN, K, nullptr);
    } else {
        id -= nblk1;
        gemm_core<BM, BN, 1, 0, 0>(As, Bs, A2, lda2, B2, ldb2, C2, ldc2,
                                    (id / nx2) * BM, (id % nx2) * BN, K, nullptr);
    }
}

// cross-attention K-proj + V^T-proj for all 6 decoder layers in ONE launch (3072 blocks)
__global__ __launch_bounds__(256) void cross_kv(
    const u16* __restrict__ Xb, const u16* __restrict__ Wd,   // Wd = Wreg + NL*WBLK
    u16* __restrict__ Kcr, u16* __restrict__ Vtc)
{
    __shared__ __align__(16) u16 As[4 * 64 * 32];
    __shared__ __align__(16) u16 Bs[4 * 64 * 32];
    int id = blockIdx.x;
    if (id < 1536) {
        int l = id >> 8, t = id & 255;                 // (32 row-tiles, 8 col-tiles)
        const u16* w = Wd + (size_t)l * 4194304u + 1310720u;   // OFF_CK
        gemm_core<64, 64, 1, 0, 0>(As, Bs, Xb, 512, w, 512,
            Kcr + (size_t)l * MTOK * 512, 512, (t >> 3) * 64, (t & 7) * 64, 512, nullptr);
    } else {
        id -= 1536;
        int l = id >> 8, t = id & 255;                 // (8 row-tiles, 32 col-tiles)
        const u16* w = Wd + (size_t)l * 4194304u + 1572864u;   // OFF_CV
        gemm_core<64, 64, 1, 0, 0>(As, Bs, w, 512, Xb, 512,
            Vtc + (size_t)l * 512 * MTOK, MTOK, (t >> 5) * 64, (t & 31) * 64, 512, nullptr);
    }
}

// ======================= flash attention (QBLK=64, 4 waves, 3-slot counted-vmcnt ring) =======================
template<int CAUSAL>
__global__ __launch_bounds__(256) void flash_attn(
    const u16* __restrict__ Qp, int ldq,
    const u16* __restrict__ Kp, int ldk,
    const u16* __restrict__ Vtp,
    u16* __restrict__ O,
    const int* __restrict__ ids)
{
    __shared__ __align__(16) u16 Kl[3][64 * 64];
    __shared__ __align__(16) u16 Vl[3][64 * 64];
    __shared__ __align__(16) u16 Pl[4][16 * 64];
    __shared__ float msk[SS];

    const int tid = threadIdx.x, lane = tid & 63, wid = tid >> 6;
    const int qt = blockIdx.x, bh = blockIdx.y;
    const int b = bh >> 3, h = bh & 7;
    const int q0 = qt * 64;

    for (int i = tid; i < SS; i += 256)
        msk[i] = (ids[b * SS + i] == PAD_ID) ? -1e30f : 0.0f;

    const int qloc = wid * 16 + (lane & 15);
    const u16* Qb = Qp + (size_t)(b * SS + q0 + qloc) * ldq + h * 64 + ((lane >> 4) * 8);
    short8 qf[2];
    qf[0] = *(const short8*)(Qb);
    qf[1] = *(const short8*)(Qb + 32);

    const u16* Kb = Kp + (size_t)b * SS * ldk + h * 64;
    const u16* Vb = Vtp + (size_t)(h * 64) * MTOK + b * SS;

    auto stage = [&](int buf, int kt) {
        int row = tid >> 3, sl = tid & 7;
        #pragma unroll
        for (int r = 0; r < 2; r++) {
            int rr = row + r * 32;
            int ls = sl ^ (rr & 7);
            gload16(Kb + (size_t)(kt * 64 + rr) * ldk + ls * 8, &Kl[buf][rr * 64 + sl * 8]);
            gload16(Vb + (size_t)rr * MTOK + kt * 64 + ls * 8, &Vl[buf][rr * 64 + sl * 8]);
        }
    };

    const int nt = CAUSAL ? (qt + 1) : (SS / 64);

    float m_i[4], l_i[4];
    f32x4 o_acc[4];
    const f32x4 zero = {0.f, 0.f, 0.f, 0.f};
    #pragma unroll
    for (int i = 0; i < 4; i++) { m_i[i] = -1e30f; l_i[i] = 0.0f; }
    #pragma unroll
    for (int n = 0; n < 4; n++) o_acc[n] = zero;

    auto comp = [&](int kt) {
        const int cur = kt % 3;
        f32x4 s_acc[4];
        #pragma unroll
        for (int n = 0; n < 4; n++) s_acc[n] = zero;
        __builtin_amdgcn_s_setprio(1);
        #pragma unroll
        for (int kk = 0; kk < 2; kk++) {
            #pragma unroll
            for (int n = 0; n < 4; n++) {
                int row = n * 16 + (lane & 15);
                int ls = (kk * 4 + (lane >> 4)) ^ (row & 7);
                short8 kf = *(const short8*)&Kl[cur][row * 64 + ls * 8];
                s_acc[n] = __builtin_amdgcn_mfma_f32_16x16x32_bf16(qf[kk], kf, s_acc[n], 0, 0, 0);
            }
        }
        __builtin_amdgcn_s_setprio(0);

        float sv[4][4];
        #pragma unroll
        for (int n = 0; n < 4; n++) {
            int kg = kt * 64 + n * 16 + (lane & 15);
            float mk = msk[kg];
            #pragma unroll
            for (int i = 0; i < 4; i++) {
                float s = s_acc[n][i] * 0.125f + mk;
                if (CAUSAL) {
                    int qg = q0 + wid * 16 + ((lane >> 4) << 2) + i;
                    if (kg > qg) s = -1e30f;
                }
                sv[n][i] = s;
            }
        }
        float pm[4], mn[4], rs[4], ps[4];
        #pragma unroll
        for (int i = 0; i < 4; i++)
            pm[i] = fmaxf(fmaxf(sv[0][i], sv[1][i]), fmaxf(sv[2][i], sv[3][i]));
        #pragma unroll
        for (int i = 0; i < 4; i++) {
            #pragma unroll
            for (int msh = 1; msh <= 8; msh <<= 1)
                pm[i] = fmaxf(pm[i], __shfl_xor(pm[i], msh));
            mn[i] = fmaxf(m_i[i], pm[i]);
            rs[i] = __expf(m_i[i] - mn[i]);
            m_i[i] = mn[i];
        }
        float p[4][4];
        #pragma unroll
        for (int n = 0; n < 4; n++)
            #pragma unroll
            for (int i = 0; i < 4; i++)
                p[n][i] = (sv[n][i] < -1e29f) ? 0.0f : __expf(sv[n][i] - mn[i]);
        #pragma unroll
        for (int i = 0; i < 4; i++) {
            ps[i] = p[0][i] + p[1][i] + p[2][i] + p[3][i];
            #pragma unroll
            for (int msh = 1; msh <= 8; msh <<= 1)
                ps[i] += __shfl_xor(ps[i], msh);
            l_i[i] = l_i[i] * rs[i] + ps[i];
        }
        #pragma unroll
        for (int n = 0; n < 4; n++)
            #pragma unroll
            for (int i = 0; i < 4; i++)
                o_acc[n][i] *= rs[i];

        #pragma unroll
        for (int n = 0; n < 4; n++) {
            int k = n * 16 + (lane & 15);
            #pragma unroll
            for (int i = 0; i < 4; i++) {
                int q = ((lane >> 4) << 2) + i;
                Pl[wid][q * 64 + (((k >> 3) ^ (q & 7)) << 3) + (k & 7)] = f2bf(p[n][i]);
            }
        }
        asm volatile("s_waitcnt lgkmcnt(0)" ::: "memory");
        __builtin_amdgcn_sched_barrier(0);

        __builtin_amdgcn_s_setprio(1);
        #pragma unroll
        for (int kk = 0; kk < 2; kk++) {
            int qrow = lane & 15;
            int lsp = (kk * 4 + (lane >> 4)) ^ (qrow & 7);
            short8 pa = *(const short8*)&Pl[wid][qrow * 64 + lsp * 8];
            #pragma unroll
            for (int nf = 0; nf < 4; nf++) {
                int row = nf * 16 + (lane & 15);
                int vs = (kk * 4 + (lane >> 4)) ^ (row & 7);
                short8 vf = *(const short8*)&Vl[cur][row * 64 + vs * 8];
                o_acc[nf] = __builtin_amdgcn_mfma_f32_16x16x32_bf16(pa, vf, o_acc[nf], 0, 0, 0);
            }
        }
        __builtin_amdgcn_s_setprio(0);
    };

    stage(0, 0);
    stage(1, 1);
    int t = 0;
    for (; t < nt - 1; ++t) {
        waitv<4>();
        rawbar();
        if (t + 2 < nt) stage((t + 2) % 3, t + 2);
        comp(t);
    }
    waitv<0>(); rawbar(); comp(nt - 1);

    #pragma unroll
    for (int nf = 0; nf < 4; nf++) {
        int d = h * 64 + nf * 16 + (lane & 15);
        #pragma unroll
        for (int i = 0; i < 4; i++) {
            int qg = b * SS + q0 + wid * 16 + ((lane >> 4) << 2) + i;
            O[(size_t)qg * DDIM + d] = f2bf(o_acc[nf][i] / l_i[i]);
        }
    }
}

// ============ transpose + convert core: dst[N,K] = bf16(src[K,N]) (64x64 tile) ============
__device__ __forceinline__ void transp_core(const float* __restrict__ src, u16* __restrict__ dst,
                                            int N, int K, int n0, int k0)
{
    __shared__ u16 t[64][65];
    const int tid = threadIdx.x;
    #pragma unroll
    for (int i = 0; i < 16; i++) {
        int idx = tid + i * 256;
        int kr = idx >> 6, nc = idx & 63;
        t[kr][nc] = f2bf(src[(size_t)(k0 + kr) * N + n0 + nc]);
    }
    __syncthreads();
    #pragma unroll
    for (int i = 0; i < 16; i++) {
        int idx = tid + i * 256;
        int nr = idx >> 6, kc = idx & 63;
        dst[(size_t)(n0 + nr) * K + k0 + kc] = t[kc][nr];
    }
}

__global__ __launch_bounds__(256) void transp(const float* __restrict__ src, u16* __restrict__ dst,
                                              int N, int K, size_t sStride, size_t dStride)
{
    transp_core(src + (size_t)blockIdx.z * sStride, dst + (size_t)blockIdx.z * dStride,
                N, K, blockIdx.x * 64, blockIdx.y * 64);
}

// ---- weight-block layout (u16 offsets) ----
#define OFF_QK 0u
#define OFF_WV 524288u
#define OFF_WO 786432u
#define OFF_CQ 1048576u
#define OFF_CK 1310720u
#define OFF_CV 1572864u
#define OFF_CO 1835008u
#define OFF_W1 2097152u
#define OFF_W2 3145728u
#define WBLK   4194304u
#define M2CNT  262144u
#define MF1CNT 1048576u

// ======== mega-prep: all weight transposes + vocab projT + BOTH embeddings in ONE launch ========
// flat grid: [0,4608) W-tiles, [4608,7680) F1, [7680,10752) F2, [10752,14752) projT,
//            [14752,18848) embed (one token per block, 256 threads x 2 elems)
__global__ __launch_bounds__(256) void transp_all(
    const float* p0, const float* p1, const float* p2, const float* p3,
    const float* p4, const float* p5, const float* p6, const float* p7,
    const float* p8, const float* p9, const float* p10, const float* p11,
    const float* ew1, const float* dw1, const float* ew2, const float* dw2,
    const float* proj, u16* __restrict__ wreg, u16* __restrict__ projT,
    const int* __restrict__ src, const int* __restrict__ trg,
    const float* __restrict__ es, const float* __restrict__ et,
    float* __restrict__ X, u16* __restrict__ Xb,
    float* __restrict__ Y, u16* __restrict__ Ybf)
{
    int jid = blockIdx.x;
    if (jid < 4608) {
        int z = jid >> 6, t = jid & 63;
        int w = z % 12, l = z / 12;
        const float* ptrs[12] = {p0,p1,p2,p3,p4,p5,p6,p7,p8,p9,p10,p11};
        const float* srcw = ptrs[w] + (size_t)l * M2CNT;
        u16* dst = wreg + (w < 4 ? (size_t)l * WBLK + (size_t)w * M2CNT
                                 : (size_t)(NL + l) * WBLK + (size_t)(w - 4) * M2CNT);
        transp_core(srcw, dst, 512, 512, (t & 7) * 64, (t >> 3) * 64);
    } else if (jid < 7680) {
        int j = jid - 4608;
        int z = j >> 8, t = j & 255;
        int l = z % NL, w = z / NL;
        const float* srcw = (w ? dw1 : ew1) + (size_t)l * MF1CNT;
        u16* dst = wreg + (size_t)(w * NL + l) * WBLK + OFF_W1;
        transp_core(srcw, dst, 2048, 512, (t % 32) * 64, (t / 32) * 64);
    } else if (jid < 10752) {
        int j = jid - 7680;
        int z = j >> 8, t = j & 255;
        int l = z % NL, w = z / NL;
        const float* srcw = (w ? dw2 : ew2) + (size_t)l * MF1CNT;
        u16* dst = wreg + (size_t)(w * NL + l) * WBLK + OFF_W2;
        transp_core(srcw, dst, 512, 2048, (t % 8) * 64, (t / 8) * 64);
    } else if (jid < 14752) {
        int j = jid - 10752;
        transp_core(proj, projT, NVOC, 512, (j % 500) * 64, (j / 500) * 64);
    } else {
        int tok = jid - 14752;                 // 0..4095
        bool dec = tok >= MTOK;
        int tk = dec ? tok - MTOK : tok;
        int pos = tk & (SS - 1);
        int id2 = (dec ? trg : src)[tk];
        const float* emb = dec ? et : es;
        float* xo = dec ? Y : X;
        u16*   bo = dec ? Ybf : Xb;
        #pragma unroll
        for (int half = 0; half < 2; half++) {
            int d = threadIdx.x + half * 256;
            int i = d >> 1;
            double freq = exp(-(2.0 * (double)i / (double)DDIM) * log(10000.0));
            double ang = (double)pos * freq;
            float pe = (float)((d & 1) ? cos(ang) : sin(ang));
            float val = emb[(size_t)id2 * DDIM + d] * 22.62741699796952f + pe;
            xo[(size_t)tk * DDIM + d] = val;
            bo[(size_t)tk * DDIM + d] = f2bf(val);
        }
    }
}

// ============ merged embedding (fallback for !full path) ============
__global__ void embed_kernel(const int* __restrict__ src, const int* __restrict__ trg,
                             const float* __restrict__ es, const float* __restrict__ et,
                             float* __restrict__ X, u16* __restrict__ Xb,
                             float* __restrict__ Y, u16* __restrict__ Ybf)
{
    int gtok = blockIdx.x;
    int d = threadIdx.x;
    bool dec = gtok >= MTOK;
    int tok = dec ? gtok - MTOK : gtok;
    int pos = tok & (SS - 1);
    int id = (dec ? trg : src)[tok];
    const float* emb = dec ? et : es;
    int i = d >> 1;
    double freq = exp(-(2.0 * (double)i / (double)DDIM) * log(10000.0));
    double ang = (double)pos * freq;
    float pe = (float)((d & 1) ? cos(ang) : sin(ang));
    float val = emb[(size_t)id * DDIM + d] * 22.62741699796952f + pe;
    (dec ? Y : X)[(size_t)tok * DDIM + d] = val;
    (dec ? Ybf : Xb)[(size_t)tok * DDIM + d] = f2bf(val);
}

// ============ NP-way split-K reducer (+opt bias) + residual add + LayerNorm ============
template<int NP, int BIAS>
__global__ __launch_bounds__(256) void add_ln_rd(float* __restrict__ x,
    const float* __restrict__ part, const float* __restrict__ bias,
    const float* __restrict__ g, const float* __restrict__ bta, u16* __restrict__ xb)
{
    int row = blockIdx.x;
    int tid = threadIdx.x;
    size_t base = (size_t)row * DDIM;
    __shared__ float sbuf[4];

    float v0 = x[base + tid]       + (BIAS ? bias[tid] : 0.0f);
    float v1 = x[base + tid + 256] + (BIAS ? bias[tid + 256] : 0.0f);
    #pragma unroll
    for (int s4 = 0; s4 < NP; s4++) {
        v0 += part[s4 * MSZE + base + tid];
        v1 += part[s4 * MSZE + base + tid + 256];
    }

    float s = v0 + v1;
    #pragma unroll
    for (int o = 32; o > 0; o >>= 1) s += __shfl_down(s, o);
    if ((tid & 63) == 0) sbuf[tid >> 6] = s;
    __syncthreads();
    float mean = (sbuf[0] + sbuf[1] + sbuf[2] + sbuf[3]) * (1.0f / DDIM);
    __syncthreads();

    float d0 = v0 - mean, d1 = v1 - mean;
    float ss = d0 * d0 + d1 * d1;
    #pragma unroll
    for (int o = 32; o > 0; o >>= 1) ss += __shfl_down(ss, o);
    if ((tid & 63) == 0) sbuf[tid >> 6] = ss;
    __syncthreads();
    float var = (sbuf[0] + sbuf[1] + sbuf[2] + sbuf[3]) * (1.0f / DDIM);
    float inv = rsqrtf(var + 1e-5f);

    float o0 = d0 * inv * g[tid]       + bta[tid];
    float o1 = d1 * inv * g[tid + 256] + bta[tid + 256];
    x[base + tid] = o0;
    x[base + tid + 256] = o1;
    xb[base + tid] = f2bf(o0);
    xb[base + tid + 256] = f2bf(o1);
}

// ======================= host orchestration =======================
extern "C" void kernel_launch(void* const* d_in, const int* in_sizes, int n_in,
                              void* d_out, int out_size, void* d_ws, size_t ws_size,
                              hipStream_t stream)
{
    (void)in_sizes; (void)n_in; (void)out_size;

    const int*   src      = (const int*)  d_in[0];
    const int*   trg      = (const int*)  d_in[1];
    const float* emb_src  = (const float*)d_in[2];
    const float* emb_trg  = (const float*)d_in[3];
    const float* enc_wq   = (const float*)d_in[4];
    const float* enc_wk   = (const float*)d_in[5];
    const float* enc_wv   = (const float*)d_in[6];
    const float* enc_wo   = (const float*)d_in[7];
    const float* enc_ln1g = (const float*)d_in[8];
    const float* enc_ln1b = (const float*)d_in[9];
    const float* enc_w1   = (const float*)d_in[10];
    const float* enc_b1   = (const float*)d_in[11];
    const float* enc_w2   = (const float*)d_in[12];
    const float* enc_b2   = (const float*)d_in[13];
    const float* enc_ln2g = (const float*)d_in[14];
    const float* enc_ln2b = (const float*)d_in[15];
    const float* dec_wq   = (const float*)d_in[16];
    const float* dec_wk   = (const float*)d_in[17];
    const float* dec_wv   = (const float*)d_in[18];
    const float* dec_wo   = (const float*)d_in[19];
    const float* dec_ln1g = (const float*)d_in[20];
    const float* dec_ln1b = (const float*)d_in[21];
    const float* dec_cq   = (const float*)d_in[22];
    const float* dec_ck   = (const float*)d_in[23];
    const float* dec_cv   = (const float*)d_in[24];
    const float* dec_co   = (const float*)d_in[25];
    const float* dec_ln2g = (const float*)d_in[26];
    const float* dec_ln2b = (const float*)d_in[27];
    const float* dec_w1   = (const float*)d_in[28];
    const float* dec_b1   = (const float*)d_in[29];
    const float* dec_w2   = (const float*)d_in[30];
    const float* dec_b2   = (const float*)d_in[31];
    const float* dec_ln3g = (const float*)d_in[32];
    const float* dec_ln3b = (const float*)d_in[33];
    const float* proj     = (const float*)d_in[34];

    float* OUT = (float*)d_out;
    char* base = (char*)d_ws;

    size_t off = 0;
    auto carve = [&](size_t bytes) { char* p = base + off; off += (bytes + 255) & ~(size_t)255; return p; };

    float* X      = (float*)carve(MSZE * 4);
    float* Yb     = (float*)carve(MSZE * 4);
    u16*   Xb     = (u16*)  carve(MSZE * 2);
    u16*   Ybf    = (u16*)  carve(MSZE * 2);
    u16*   QKb    = (u16*)  carve((size_t)MTOK * 1024 * 2);
    u16*   Vt     = (u16*)  carve((size_t)512 * MTOK * 2);
    u16*   CTX    = (u16*)  carve(MSZE * 2);
    u16*   HFF    = (u16*)  carve((size_t)MTOK * FFN * 2);
    u16*   Kcr    = (u16*)  carve((size_t)NL * MTOK * 512 * 2);
    u16*   Vtc    = (u16*)  carve((size_t)NL * 512 * MTOK * 2);
    u16*   projT  = (u16*)  carve((size_t)NVOC * 512 * 2);
    float* Tp4    = (float*)carve((size_t)4 * MSZE * 4);       // split-K partials (shared)

    const size_t WFULL_B = (size_t)12 * WBLK * 2;
    bool full = (ws_size >= off + WFULL_B);
    u16* Wreg = (u16*)carve(full ? WFULL_B : (size_t)WBLK * 2);

    auto T = [&](const float* s, u16* d, int Kd, int Nd, size_t ss, size_t ds, int L) {
        transp<<<dim3(Nd / 64, Kd / 64, L), 256, 0, stream>>>(s, d, Nd, Kd, ss, ds);
    };

    // ---- one-time prep: transposes + projT + embeddings in a single launch ----
    if (full) {
        transp_all<<<dim3(18848), 256, 0, stream>>>(
            enc_wq, enc_wk, enc_wv, enc_wo,
            dec_wq, dec_wk, dec_wv, dec_wo,
            dec_cq, dec_ck, dec_cv, dec_co,
            enc_w1, dec_w1, enc_w2, dec_w2,
            proj, Wreg, projT,
            src, trg, emb_src, emb_trg, X, Xb, Yb, Ybf);
    } else {
        T(proj, projT, 512, NVOC, 0, 0, 1);
        embed_kernel<<<2 * MTOK, DDIM, 0, stream>>>(src, trg, emb_src, emb_trg, X, Xb, Yb, Ybf);
    }

    // self-attention: (QK-proj ∥ V^T-proj) dual 64² GEMM (768 blocks) + flash (256 blocks)
    //                 + O-proj split-K2 (512 blocks) -> Tp4[0..1]
    auto self_attn = [&](const u16* xsrc, const u16* wb, const int* mask_ids, int causal) {
        mgemm_dual<64, 64><<<dim3(768), 256, 0, stream>>>(
            xsrc, 512, wb + OFF_QK, 512, QKb, 1024, 16, 512,
            wb + OFF_WV, 512, xsrc, 512, Vt, MTOK, 32,
            512);
        if (causal)
            flash_attn<1><<<dim3(8, 32), 256, 0, stream>>>(QKb, 1024, QKb + 512, 1024, Vt, CTX, mask_ids);
        else
            flash_attn<0><<<dim3(8, 32), 256, 0, stream>>>(QKb, 1024, QKb + 512, 1024, Vt, CTX, mask_ids);
        mgemm<64, 64, 0, 0, 0><<<dim3(8, 32, 2), 256, 0, stream>>>(
            CTX, 512, 0, 256, wb + OFF_WO, 512, 0, 256, Tp4, 512, 0, MSZE, 256, nullptr);
    };

    auto o_proj_sk2 = [&](const u16* a, const u16* w) {
        mgemm<64, 64, 0, 0, 0><<<dim3(8, 32, 2), 256, 0, stream>>>(
            a, 512, 0, 256, w, 512, 0, 256, Tp4, 512, 0, MSZE, 256, nullptr);
    };

    // FFN: W1 64² (1024 blocks, relu+bias) then W2 split-K(4x512) 64² (1024 blocks) -> Tp4[0..3]
    auto ffn = [&](const u16* xsrc, const u16* wb, const float* b1) {
        mgemm<64, 64, 1, 1, 1><<<dim3(32, 32, 1), 256, 0, stream>>>(
            xsrc, 512, 0, 0, wb + OFF_W1, 512, 0, 0, HFF, FFN, 0, 0, 512, b1);
        mgemm<64, 64, 0, 0, 0><<<dim3(8, 32, 4), 256, 0, stream>>>(
            HFF, 2048, 0, 512, wb + OFF_W2, 2048, 0, 512,
            Tp4, 512, 0, MSZE, 512, nullptr);
    };

    const size_t M2 = M2CNT, MF1 = MF1CNT;

    // ---- encoder ----
    for (int l = 0; l < NL; l++) {
        u16* wb;
        if (full) wb = Wreg + (size_t)l * WBLK;
        else {
            wb = Wreg;
            T(enc_wq + l * M2,  wb + OFF_QK,      512, 512,  0, 0, 1);
            T(enc_wk + l * M2,  wb + OFF_QK + M2, 512, 512,  0, 0, 1);
            T(enc_wv + l * M2,  wb + OFF_WV,      512, 512,  0, 0, 1);
            T(enc_wo + l * M2,  wb + OFF_WO,      512, 512,  0, 0, 1);
            T(enc_w1 + l * MF1, wb + OFF_W1,      512, 2048, 0, 0, 1);
            T(enc_w2 + l * MF1, wb + OFF_W2,      2048, 512, 0, 0, 1);
        }
        self_attn(Xb, wb, src, 0);
        add_ln_rd<2, 0><<<MTOK, 256, 0, stream>>>(X, Tp4, nullptr,
            enc_ln1g + l * DDIM, enc_ln1b + l * DDIM, Xb);
        ffn(Xb, wb, enc_b1 + l * FFN);
        add_ln_rd<4, 1><<<MTOK, 256, 0, stream>>>(X, Tp4, enc_b2 + l * DDIM,
            enc_ln2g + l * DDIM, enc_ln2b + l * DDIM, Xb);
    }

    // ---- cross-attention K / V^T for all 6 decoder layers (single launch) ----
    if (full) {
        cross_kv<<<dim3(3072), 256, 0, stream>>>(Xb, Wreg + (size_t)NL * WBLK, Kcr, Vtc);
    }

    // ---- decoder ----
    for (int l = 0; l < NL; l++) {
        u16* wb;
        if (full) wb = Wreg + (size_t)(NL + l) * WBLK;
        else {
            wb = Wreg;
            T(dec_wq + l * M2,  wb + OFF_QK,      512, 512,  0, 0, 1);
            T(dec_wk + l * M2,  wb + OFF_QK + M2, 512, 512,  0, 0, 1);
            T(dec_wv + l * M2,  wb + OFF_WV,      512, 512,  0, 0, 1);
            T(dec_wo + l * M2,  wb + OFF_WO,      512, 512,  0, 0, 1);
            T(dec_cq + l * M2,  wb + OFF_CQ,      512, 512,  0, 0, 1);
            T(dec_ck + l * M2,  wb + OFF_CK,      512, 512,  0, 0, 1);
            T(dec_cv + l * M2,  wb + OFF_CV,      512, 512,  0, 0, 1);
            T(dec_co + l * M2,  wb + OFF_CO,      512, 512,  0, 0, 1);
            T(dec_w1 + l * MF1, wb + OFF_W1,      512, 2048, 0, 0, 1);
            T(dec_w2 + l * MF1, wb + OFF_W2,      2048, 512, 0, 0, 1);
            mgemm<64, 64, 1, 0, 0><<<dim3(8, 32, 1), 256, 0, stream>>>(
                Xb, 512, 0, 0, wb + OFF_CK, 512, 0, 0, Kcr + (size_t)l * MTOK * 512, 512, 0, 0, 512, nullptr);
            mgemm<64, 64, 1, 0, 0><<<dim3(32, 8, 1), 256, 0, stream>>>(
                wb + OFF_CV, 512, 0, 0, Xb, 512, 0, 0, Vtc + (size_t)l * 512 * MTOK, MTOK, 0, 0, 512, nullptr);
        }
        // masked self-attention (O-proj split-K2 -> Tp4)
        self_attn(Ybf, wb, trg, 1);
        add_ln_rd<2, 0><<<MTOK, 256, 0, stream>>>(Yb, Tp4, nullptr,
            dec_ln1g + l * DDIM, dec_ln1b + l * DDIM, Ybf);
        // cross-attention
        mgemm<64, 64, 1, 0, 0><<<dim3(8, 32, 1), 256, 0, stream>>>(
            Ybf, 512, 0, 0, wb + OFF_CQ, 512, 0, 0, QKb, 1024, 0, 0, 512, nullptr);
        flash_attn<0><<<dim3(8, 32), 256, 0, stream>>>(
            QKb, 1024, Kcr + (size_t)l * MTOK * 512, 512, Vtc + (size_t)l * 512 * MTOK, CTX, src);
        o_proj_sk2(CTX, wb + OFF_CO);
        add_ln_rd<2, 0><<<MTOK, 256, 0, stream>>>(Yb, Tp4, nullptr,
            dec_ln2g + l * DDIM, dec_ln2b + l * DDIM, Ybf);
        // FFN
        ffn(Ybf, wb, dec_b1 + l * FFN);
        add_ln_rd<4, 1><<<MTOK, 256, 0, stream>>>(Yb, Tp4, dec_b2 + l * DDIM,
            dec_ln3g + l * DDIM, dec_ln3b + l * DDIM, Ybf);
    }

    // ---- final vocab projection (256x128 tile, XCD-swizzled; 2000 blocks, 2000 % 8 == 0) ----
    mgemm<256, 128, 0, 0, 0, 1><<<dim3(NVOC / 128, MTOK / 256, 1), 256, 0, stream>>>(
        Ybf, 512, 0, 0, projT, 512, 0, 0, OUT, NVOC, 0, 0, 512, nullptr);
}

// Round 14
// 1431.550 us; speedup vs baseline: 1.0276x; 1.0276x over previous
//
#include <hip/hip_runtime.h>
#include <math.h>

// ---------------- problem constants ----------------
#define BBATCH 4
#define SS 512
#define DDIM 512
#define FFN 2048
#define NHEAD 8
#define DHEAD 64
#define NL 6
#define NVOC 32000
#define MTOK (BBATCH*SS)       // 2048
#define PAD_ID 0
#define MSZE ((size_t)MTOK * DDIM)   // 1,048,576 elements

typedef unsigned short u16;
typedef __attribute__((ext_vector_type(8))) short short8;   // 8 bf16 (4 VGPRs)
typedef __attribute__((ext_vector_type(4))) float f32x4;

__device__ __forceinline__ u16 f2bf(float f) {
    union { float f; unsigned u; } v; v.f = f;
    unsigned r = ((v.u >> 16) & 1u) + 0x7fffu;   // round-to-nearest-even
    return (u16)((v.u + r) >> 16);
}

__device__ __forceinline__ void gload16(const u16* g, u16* l) {
    __builtin_amdgcn_global_load_lds(
        (const __attribute__((address_space(1))) void*)g,
        (__attribute__((address_space(3))) void*)l, 16, 0, 0);
}

// counted vmcnt wait (literal-immediate) + scheduling fence (rule #18)
template<int N> __device__ __forceinline__ void waitv() {
    if constexpr (N == 0)       asm volatile("s_waitcnt vmcnt(0)" ::: "memory");
    else if constexpr (N == 2)  asm volatile("s_waitcnt vmcnt(2)" ::: "memory");
    else if constexpr (N == 4)  asm volatile("s_waitcnt vmcnt(4)" ::: "memory");
    else if constexpr (N == 6)  asm volatile("s_waitcnt vmcnt(6)" ::: "memory");
    else if constexpr (N == 8)  asm volatile("s_waitcnt vmcnt(8)" ::: "memory");
    else if constexpr (N == 12) asm volatile("s_waitcnt vmcnt(12)" ::: "memory");
    __builtin_amdgcn_sched_barrier(0);
}
__device__ __forceinline__ void rawbar() {
    __builtin_amdgcn_s_barrier();
    __builtin_amdgcn_sched_barrier(0);
}

// ======================= MFMA GEMM core (NT): C[M,N] = A[M,K] * B[N,K]^T =======================
// 4-slot LDS ring, 3 tiles in flight (counted vmcnt). 256 threads = 4 waves (2x2).
template<int BM, int BN, int OUTBF, int RELU, int BIAS>
__device__ __forceinline__ void gemm_core(
    u16* __restrict__ AsB, u16* __restrict__ BsB,     // 4*BM*32 / 4*BN*32
    const u16* __restrict__ A, int lda,
    const u16* __restrict__ B, int ldb,
    void* __restrict__ Cv, int ldc,
    int row0, int col0, int K, const float* __restrict__ bias)
{
    const int tid  = threadIdx.x;
    const int lane = tid & 63;
    const int wid  = tid >> 6;
    const int wr   = wid >> 1, wc = wid & 1;
    constexpr int MF = BM / 32, NF = BN / 32, RA = BM / 64, RB = BN / 64;
    constexpr int LPT = RA + RB;

    const u16* aSrc[RA]; int aOff[RA];
    #pragma unroll
    for (int r = 0; r < RA; r++) {
        int row = (tid >> 2) + r * 64;
        int slot = ((tid & 3) << 4) ^ ((row & 3) << 4);
        aSrc[r] = A + (size_t)(row0 + row) * lda + (slot >> 1);
        aOff[r] = r * 2048 + tid * 8;
    }
    const u16* bSrc[RB]; int bOff[RB];
    #pragma unroll
    for (int r = 0; r < RB; r++) {
        int row = (tid >> 2) + r * 64;
        int slot = ((tid & 3) << 4) ^ ((row & 3) << 4);
        bSrc[r] = B + (size_t)(col0 + row) * ldb + (slot >> 1);
        bOff[r] = r * 2048 + tid * 8;
    }

    f32x4 acc[MF][NF];
    const f32x4 zero = {0.f, 0.f, 0.f, 0.f};
    #pragma unroll
    for (int m = 0; m < MF; m++)
        #pragma unroll
        for (int n = 0; n < NF; n++) acc[m][n] = zero;

    auto issue = [&](int t) {
        u16* ad = AsB + (t & 3) * (BM * 32);
        u16* bd = BsB + (t & 3) * (BN * 32);
        #pragma unroll
        for (int r = 0; r < RA; r++) gload16(aSrc[r] + t * 32, ad + aOff[r]);
        #pragma unroll
        for (int r = 0; r < RB; r++) gload16(bSrc[r] + t * 32, bd + bOff[r]);
    };
    auto comp = [&](int t) {
        const u16* as = AsB + (t & 3) * (BM * 32);
        const u16* bs = BsB + (t & 3) * (BN * 32);
        short8 af[MF], bf[NF];
        #pragma unroll
        for (int m = 0; m < MF; m++) {
            int row = wr * (BM / 2) + m * 16 + (lane & 15);
            int slot = ((lane >> 4) << 4) ^ ((row & 3) << 4);
            af[m] = *(const short8*)&as[row * 32 + (slot >> 1)];
        }
        #pragma unroll
        for (int n = 0; n < NF; n++) {
            int row = wc * (BN / 2) + n * 16 + (lane & 15);
            int slot = ((lane >> 4) << 4) ^ ((row & 3) << 4);
            bf[n] = *(const short8*)&bs[row * 32 + (slot >> 1)];
        }
        __builtin_amdgcn_s_setprio(1);
        #pragma unroll
        for (int m = 0; m < MF; m++)
            #pragma unroll
            for (int n = 0; n < NF; n++)
                acc[m][n] = __builtin_amdgcn_mfma_f32_16x16x32_bf16(af[m], bf[n], acc[m][n], 0, 0, 0);
        __builtin_amdgcn_s_setprio(0);
    };

    const int nt = K / 32;
    issue(0); issue(1); issue(2);
    int t = 0;
    for (; t < nt - 2; ++t) {
        waitv<2 * LPT>();
        rawbar();
        if (t + 3 < nt) issue(t + 3);
        comp(t);
    }
    waitv<LPT>(); rawbar(); comp(nt - 2);
    waitv<0>();   rawbar(); comp(nt - 1);

    const int crow = row0 + wr * (BM / 2);
    const int ccol = col0 + wc * (BN / 2);
    #pragma unroll
    for (int m = 0; m < MF; m++) {
        #pragma unroll
        for (int n = 0; n < NF; n++) {
            int col = ccol + n * 16 + (lane & 15);
            float bv = BIAS ? bias[col] : 0.0f;
            #pragma unroll
            for (int i = 0; i < 4; i++) {
                int row = crow + m * 16 + ((lane >> 4) << 2) + i;
                float v = acc[m][n][i] + bv;
                if (RELU) v = fmaxf(v, 0.0f);
                if (OUTBF) ((u16*)Cv)[(size_t)row * ldc + col] = f2bf(v);
                else       ((float*)Cv)[(size_t)row * ldc + col] = v;
            }
        }
    }
}

// batched/swizzled wrapper (z: zb = z>>3 batch stride, zh = z&7 head/split stride)
template<int BM, int BN, int OUTBF, int RELU, int BIAS, int SWZ = 0>
__global__ __launch_bounds__(256) void mgemm(
    const u16* __restrict__ A, int lda, size_t aSb, size_t aSh,
    const u16* __restrict__ B, int ldb, size_t bSb, size_t bSh,
    void* __restrict__ Cv, int ldc, size_t cSb, size_t cSh,
    int K, const float* __restrict__ bias)
{
    __shared__ __align__(16) u16 As[4 * BM * 32];
    __shared__ __align__(16) u16 Bs[4 * BN * 32];
    int bx = blockIdx.x, by = blockIdx.y;
    if (SWZ) {
        int nwg = gridDim.x * gridDim.y;
        int lin = by * gridDim.x + bx;
        int cpx = nwg >> 3;
        int s = (lin & 7) * cpx + (lin >> 3);
        bx = s % gridDim.x; by = s / gridDim.x;
    }
    const int zb = blockIdx.z >> 3, zh = blockIdx.z & 7;
    const u16* Ab = A + (size_t)zb * aSb + (size_t)zh * aSh;
    const u16* Bb = B + (size_t)zb * bSb + (size_t)zh * bSh;
    void* Cb = OUTBF ? (void*)((u16*)Cv + (size_t)zb * cSb + (size_t)zh * cSh)
                     : (void*)((float*)Cv + (size_t)zb * cSb + (size_t)zh * cSh);
    gemm_core<BM, BN, OUTBF, RELU, BIAS>(As, Bs, Ab, lda, Bb, ldb, Cb, ldc,
                                          by * BM, bx * BN, K, bias);
}

// dual-job GEMM: two independent NT gemms in one launch (bf16 out, no bias)
template<int BM, int BN>
__global__ __launch_bounds__(256) void mgemm_dual(
    const u16* __restrict__ A1, int lda1, const u16* __restrict__ B1, int ldb1,
    u16* __restrict__ C1, int ldc1, int nx1, int nblk1,
    const u16* __restrict__ A2, int lda2, const u16* __restrict__ B2, int ldb2,
    u16* __restrict__ C2, int ldc2, int nx2,
    int K)
{
    __shared__ __align__(16) u16 As[4 * BM * 32];
    __shared__ __align__(16) u16 Bs[4 * BN * 32];
    int id = blockIdx.x;
    if (id < nblk1) {
        gemm_core<BM, BN, 1, 0, 0>(As, Bs, A1, lda1, B1, ldb1, C1, ldc1,
                                    (id / nx1) * BM, (id % nx1) * BN, K, nullptr);
    } else {
        id -= nblk1;
        gemm_core<BM, BN, 1, 0, 0>(As, Bs, A2, lda2, B2, ldb2, C2, ldc2,
                                    (id / nx2) * BM, (id % nx2) * BN, K, nullptr);
    }
}

// cross-attention K-proj + V^T-proj for all 6 decoder layers in ONE launch (3072 blocks)
__global__ __launch_bounds__(256) void cross_kv(
    const u16* __restrict__ Xb, const u16* __restrict__ Wd,   // Wd = Wreg + NL*WBLK
    u16* __restrict__ Kcr, u16* __restrict__ Vtc)
{
    __shared__ __align__(16) u16 As[4 * 64 * 32];
    __shared__ __align__(16) u16 Bs[4 * 64 * 32];
    int id = blockIdx.x;
    if (id < 1536) {
        int l = id >> 8, t = id & 255;                 // (32 row-tiles, 8 col-tiles)
        const u16* w = Wd + (size_t)l * 4194304u + 1310720u;   // OFF_CK
        gemm_core<64, 64, 1, 0, 0>(As, Bs, Xb, 512, w, 512,
            Kcr + (size_t)l * MTOK * 512, 512, (t >> 3) * 64, (t & 7) * 64, 512, nullptr);
    } else {
        id -= 1536;
        int l = id >> 8, t = id & 255;                 // (8 row-tiles, 32 col-tiles)
        const u16* w = Wd + (size_t)l * 4194304u + 1572864u;   // OFF_CV
        gemm_core<64, 64, 1, 0, 0>(As, Bs, w, 512, Xb, 512,
            Vtc + (size_t)l * 512 * MTOK, MTOK, (t >> 5) * 64, (t & 31) * 64, 512, nullptr);
    }
}

// ======================= flash attention (QBLK=64, 4 waves, 3-slot counted-vmcnt ring) =======================
template<int CAUSAL>
__global__ __launch_bounds__(256) void flash_attn(
    const u16* __restrict__ Qp, int ldq,
    const u16* __restrict__ Kp, int ldk,
    const u16* __restrict__ Vtp,
    u16* __restrict__ O,
    const int* __restrict__ ids)
{
    __shared__ __align__(16) u16 Kl[3][64 * 64];
    __shared__ __align__(16) u16 Vl[3][64 * 64];
    __shared__ __align__(16) u16 Pl[4][16 * 64];
    __shared__ float msk[SS];

    const int tid = threadIdx.x, lane = tid & 63, wid = tid >> 6;
    const int qt = blockIdx.x, bh = blockIdx.y;
    const int b = bh >> 3, h = bh & 7;
    const int q0 = qt * 64;

    for (int i = tid; i < SS; i += 256)
        msk[i] = (ids[b * SS + i] == PAD_ID) ? -1e30f : 0.0f;

    const int qloc = wid * 16 + (lane & 15);
    const u16* Qb = Qp + (size_t)(b * SS + q0 + qloc) * ldq + h * 64 + ((lane >> 4) * 8);
    short8 qf[2];
    qf[0] = *(const short8*)(Qb);
    qf[1] = *(const short8*)(Qb + 32);

    const u16* Kb = Kp + (size_t)b * SS * ldk + h * 64;
    const u16* Vb = Vtp + (size_t)(h * 64) * MTOK + b * SS;

    auto stage = [&](int buf, int kt) {
        int row = tid >> 3, sl = tid & 7;
        #pragma unroll
        for (int r = 0; r < 2; r++) {
            int rr = row + r * 32;
            int ls = sl ^ (rr & 7);
            gload16(Kb + (size_t)(kt * 64 + rr) * ldk + ls * 8, &Kl[buf][rr * 64 + sl * 8]);
            gload16(Vb + (size_t)rr * MTOK + kt * 64 + ls * 8, &Vl[buf][rr * 64 + sl * 8]);
        }
    };

    const int nt = CAUSAL ? (qt + 1) : (SS / 64);

    float m_i[4], l_i[4];
    f32x4 o_acc[4];
    const f32x4 zero = {0.f, 0.f, 0.f, 0.f};
    #pragma unroll
    for (int i = 0; i < 4; i++) { m_i[i] = -1e30f; l_i[i] = 0.0f; }
    #pragma unroll
    for (int n = 0; n < 4; n++) o_acc[n] = zero;

    auto comp = [&](int kt) {
        const int cur = kt % 3;
        f32x4 s_acc[4];
        #pragma unroll
        for (int n = 0; n < 4; n++) s_acc[n] = zero;
        __builtin_amdgcn_s_setprio(1);
        #pragma unroll
        for (int kk = 0; kk < 2; kk++) {
            #pragma unroll
            for (int n = 0; n < 4; n++) {
                int row = n * 16 + (lane & 15);
                int ls = (kk * 4 + (lane >> 4)) ^ (row & 7);
                short8 kf = *(const short8*)&Kl[cur][row * 64 + ls * 8];
                s_acc[n] = __builtin_amdgcn_mfma_f32_16x16x32_bf16(qf[kk], kf, s_acc[n], 0, 0, 0);
            }
        }
        __builtin_amdgcn_s_setprio(0);

        float sv[4][4];
        #pragma unroll
        for (int n = 0; n < 4; n++) {
            int kg = kt * 64 + n * 16 + (lane & 15);
            float mk = msk[kg];
            #pragma unroll
            for (int i = 0; i < 4; i++) {
                float s = s_acc[n][i] * 0.125f + mk;
                if (CAUSAL) {
                    int qg = q0 + wid * 16 + ((lane >> 4) << 2) + i;
                    if (kg > qg) s = -1e30f;
                }
                sv[n][i] = s;
            }
        }
        float pm[4], mn[4], rs[4], ps[4];
        #pragma unroll
        for (int i = 0; i < 4; i++)
            pm[i] = fmaxf(fmaxf(sv[0][i], sv[1][i]), fmaxf(sv[2][i], sv[3][i]));
        #pragma unroll
        for (int i = 0; i < 4; i++) {
            #pragma unroll
            for (int msh = 1; msh <= 8; msh <<= 1)
                pm[i] = fmaxf(pm[i], __shfl_xor(pm[i], msh));
            mn[i] = fmaxf(m_i[i], pm[i]);
            rs[i] = __expf(m_i[i] - mn[i]);
            m_i[i] = mn[i];
        }
        float p[4][4];
        #pragma unroll
        for (int n = 0; n < 4; n++)
            #pragma unroll
            for (int i = 0; i < 4; i++)
                p[n][i] = (sv[n][i] < -1e29f) ? 0.0f : __expf(sv[n][i] - mn[i]);
        #pragma unroll
        for (int i = 0; i < 4; i++) {
            ps[i] = p[0][i] + p[1][i] + p[2][i] + p[3][i];
            #pragma unroll
            for (int msh = 1; msh <= 8; msh <<= 1)
                ps[i] += __shfl_xor(ps[i], msh);
            l_i[i] = l_i[i] * rs[i] + ps[i];
        }
        #pragma unroll
        for (int n = 0; n < 4; n++)
            #pragma unroll
            for (int i = 0; i < 4; i++)
                o_acc[n][i] *= rs[i];

        #pragma unroll
        for (int n = 0; n < 4; n++) {
            int k = n * 16 + (lane & 15);
            #pragma unroll
            for (int i = 0; i < 4; i++) {
                int q = ((lane >> 4) << 2) + i;
                Pl[wid][q * 64 + (((k >> 3) ^ (q & 7)) << 3) + (k & 7)] = f2bf(p[n][i]);
            }
        }
        asm volatile("s_waitcnt lgkmcnt(0)" ::: "memory");
        __builtin_amdgcn_sched_barrier(0);

        __builtin_amdgcn_s_setprio(1);
        #pragma unroll
        for (int kk = 0; kk < 2; kk++) {
            int qrow = lane & 15;
            int lsp = (kk * 4 + (lane >> 4)) ^ (qrow & 7);
            short8 pa = *(const short8*)&Pl[wid][qrow * 64 + lsp * 8];
            #pragma unroll
            for (int nf = 0; nf < 4; nf++) {
                int row = nf * 16 + (lane & 15);
                int vs = (kk * 4 + (lane >> 4)) ^ (row & 7);
                short8 vf = *(const short8*)&Vl[cur][row * 64 + vs * 8];
                o_acc[nf] = __builtin_amdgcn_mfma_f32_16x16x32_bf16(pa, vf, o_acc[nf], 0, 0, 0);
            }
        }
        __builtin_amdgcn_s_setprio(0);
    };

    stage(0, 0);
    stage(1, 1);
    int t = 0;
    for (; t < nt - 1; ++t) {
        waitv<4>();
        rawbar();
        if (t + 2 < nt) stage((t + 2) % 3, t + 2);
        comp(t);
    }
    waitv<0>(); rawbar(); comp(nt - 1);

    #pragma unroll
    for (int nf = 0; nf < 4; nf++) {
        int d = h * 64 + nf * 16 + (lane & 15);
        #pragma unroll
        for (int i = 0; i < 4; i++) {
            int qg = b * SS + q0 + wid * 16 + ((lane >> 4) << 2) + i;
            O[(size_t)qg * DDIM + d] = f2bf(o_acc[nf][i] / l_i[i]);
        }
    }
}

// ============ transpose + convert core: dst[N,K] = bf16(src[K,N]) (64x64 tile) ============
__device__ __forceinline__ void transp_core(const float* __restrict__ src, u16* __restrict__ dst,
                                            int N, int K, int n0, int k0)
{
    __shared__ u16 t[64][65];
    const int tid = threadIdx.x;
    #pragma unroll
    for (int i = 0; i < 16; i++) {
        int idx = tid + i * 256;
        int kr = idx >> 6, nc = idx & 63;
        t[kr][nc] = f2bf(src[(size_t)(k0 + kr) * N + n0 + nc]);
    }
    __syncthreads();
    #pragma unroll
    for (int i = 0; i < 16; i++) {
        int idx = tid + i * 256;
        int nr = idx >> 6, kc = idx & 63;
        dst[(size_t)(n0 + nr) * K + k0 + kc] = t[kc][nr];
    }
}

__global__ __launch_bounds__(256) void transp(const float* __restrict__ src, u16* __restrict__ dst,
                                              int N, int K, size_t sStride, size_t dStride)
{
    transp_core(src + (size_t)blockIdx.z * sStride, dst + (size_t)blockIdx.z * dStride,
                N, K, blockIdx.x * 64, blockIdx.y * 64);
}

// ---- weight-block layout (u16 offsets) ----
#define OFF_QK 0u
#define OFF_WV 524288u
#define OFF_WO 786432u
#define OFF_CQ 1048576u
#define OFF_CK 1310720u
#define OFF_CV 1572864u
#define OFF_CO 1835008u
#define OFF_W1 2097152u
#define OFF_W2 3145728u
#define WBLK   4194304u
#define M2CNT  262144u
#define MF1CNT 1048576u

// ======== mega-prep: all weight transposes + vocab projT + BOTH embeddings in ONE launch ========
// flat grid: [0,4608) W-tiles, [4608,7680) F1, [7680,10752) F2, [10752,14752) projT,
//            [14752,18848) embed (one token per block, 256 threads x 2 elems)
__global__ __launch_bounds__(256) void transp_all(
    const float* p0, const float* p1, const float* p2, const float* p3,
    const float* p4, const float* p5, const float* p6, const float* p7,
    const float* p8, const float* p9, const float* p10, const float* p11,
    const float* ew1, const float* dw1, const float* ew2, const float* dw2,
    const float* proj, u16* __restrict__ wreg, u16* __restrict__ projT,
    const int* __restrict__ src, const int* __restrict__ trg,
    const float* __restrict__ es, const float* __restrict__ et,
    float* __restrict__ X, u16* __restrict__ Xb,
    float* __restrict__ Y, u16* __restrict__ Ybf)
{
    int jid = blockIdx.x;
    if (jid < 4608) {
        int z = jid >> 6, t = jid & 63;
        int w = z % 12, l = z / 12;
        const float* ptrs[12] = {p0,p1,p2,p3,p4,p5,p6,p7,p8,p9,p10,p11};
        const float* srcw = ptrs[w] + (size_t)l * M2CNT;
        u16* dst = wreg + (w < 4 ? (size_t)l * WBLK + (size_t)w * M2CNT
                                 : (size_t)(NL + l) * WBLK + (size_t)(w - 4) * M2CNT);
        transp_core(srcw, dst, 512, 512, (t & 7) * 64, (t >> 3) * 64);
    } else if (jid < 7680) {
        int j = jid - 4608;
        int z = j >> 8, t = j & 255;
        int l = z % NL, w = z / NL;
        const float* srcw = (w ? dw1 : ew1) + (size_t)l * MF1CNT;
        u16* dst = wreg + (size_t)(w * NL + l) * WBLK + OFF_W1;
        transp_core(srcw, dst, 2048, 512, (t % 32) * 64, (t / 32) * 64);
    } else if (jid < 10752) {
        int j = jid - 7680;
        int z = j >> 8, t = j & 255;
        int l = z % NL, w = z / NL;
        const float* srcw = (w ? dw2 : ew2) + (size_t)l * MF1CNT;
        u16* dst = wreg + (size_t)(w * NL + l) * WBLK + OFF_W2;
        transp_core(srcw, dst, 512, 2048, (t % 8) * 64, (t / 8) * 64);
    } else if (jid < 14752) {
        int j = jid - 10752;
        transp_core(proj, projT, NVOC, 512, (j % 500) * 64, (j / 500) * 64);
    } else {
        int tok = jid - 14752;                 // 0..4095
        bool dec = tok >= MTOK;
        int tk = dec ? tok - MTOK : tok;
        int pos = tk & (SS - 1);
        int id2 = (dec ? trg : src)[tk];
        const float* emb = dec ? et : es;
        float* xo = dec ? Y : X;
        u16*   bo = dec ? Ybf : Xb;
        #pragma unroll
        for (int half = 0; half < 2; half++) {
            int d = threadIdx.x + half * 256;
            int i = d >> 1;
            double freq = exp(-(2.0 * (double)i / (double)DDIM) * log(10000.0));
            double ang = (double)pos * freq;
            float pe = (float)((d & 1) ? cos(ang) : sin(ang));
            float val = emb[(size_t)id2 * DDIM + d] * 22.62741699796952f + pe;
            xo[(size_t)tk * DDIM + d] = val;
            bo[(size_t)tk * DDIM + d] = f2bf(val);
        }
    }
}

// ============ merged embedding (fallback for !full path) ============
__global__ void embed_kernel(const int* __restrict__ src, const int* __restrict__ trg,
                             const float* __restrict__ es, const float* __restrict__ et,
                             float* __restrict__ X, u16* __restrict__ Xb,
                             float* __restrict__ Y, u16* __restrict__ Ybf)
{
    int gtok = blockIdx.x;
    int d = threadIdx.x;
    bool dec = gtok >= MTOK;
    int tok = dec ? gtok - MTOK : gtok;
    int pos = tok & (SS - 1);
    int id = (dec ? trg : src)[tok];
    const float* emb = dec ? et : es;
    int i = d >> 1;
    double freq = exp(-(2.0 * (double)i / (double)DDIM) * log(10000.0));
    double ang = (double)pos * freq;
    float pe = (float)((d & 1) ? cos(ang) : sin(ang));
    float val = emb[(size_t)id * DDIM + d] * 22.62741699796952f + pe;
    (dec ? Y : X)[(size_t)tok * DDIM + d] = val;
    (dec ? Ybf : Xb)[(size_t)tok * DDIM + d] = f2bf(val);
}

// ============ NP-way split-K reducer (+opt bias) + residual add + LayerNorm ============
template<int NP, int BIAS>
__global__ __launch_bounds__(256) void add_ln_rd(float* __restrict__ x,
    const float* __restrict__ part, const float* __restrict__ bias,
    const float* __restrict__ g, const float* __restrict__ bta, u16* __restrict__ xb)
{
    int row = blockIdx.x;
    int tid = threadIdx.x;
    size_t base = (size_t)row * DDIM;
    __shared__ float sbuf[4];

    float v0 = x[base + tid]       + (BIAS ? bias[tid] : 0.0f);
    float v1 = x[base + tid + 256] + (BIAS ? bias[tid + 256] : 0.0f);
    #pragma unroll
    for (int s4 = 0; s4 < NP; s4++) {
        v0 += part[s4 * MSZE + base + tid];
        v1 += part[s4 * MSZE + base + tid + 256];
    }

    float s = v0 + v1;
    #pragma unroll
    for (int o = 32; o > 0; o >>= 1) s += __shfl_down(s, o);
    if ((tid & 63) == 0) sbuf[tid >> 6] = s;
    __syncthreads();
    float mean = (sbuf[0] + sbuf[1] + sbuf[2] + sbuf[3]) * (1.0f / DDIM);
    __syncthreads();

    float d0 = v0 - mean, d1 = v1 - mean;
    float ss = d0 * d0 + d1 * d1;
    #pragma unroll
    for (int o = 32; o > 0; o >>= 1) ss += __shfl_down(ss, o);
    if ((tid & 63) == 0) sbuf[tid >> 6] = ss;
    __syncthreads();
    float var = (sbuf[0] + sbuf[1] + sbuf[2] + sbuf[3]) * (1.0f / DDIM);
    float inv = rsqrtf(var + 1e-5f);

    float o0 = d0 * inv * g[tid]       + bta[tid];
    float o1 = d1 * inv * g[tid + 256] + bta[tid + 256];
    x[base + tid] = o0;
    x[base + tid + 256] = o1;
    xb[base + tid] = f2bf(o0);
    xb[base + tid + 256] = f2bf(o1);
}

// ======================= host orchestration =======================
extern "C" void kernel_launch(void* const* d_in, const int* in_sizes, int n_in,
                              void* d_out, int out_size, void* d_ws, size_t ws_size,
                              hipStream_t stream)
{
    (void)in_sizes; (void)n_in; (void)out_size;

    const int*   src      = (const int*)  d_in[0];
    const int*   trg      = (const int*)  d_in[1];
    const float* emb_src  = (const float*)d_in[2];
    const float* emb_trg  = (const float*)d_in[3];
    const float* enc_wq   = (const float*)d_in[4];
    const float* enc_wk   = (const float*)d_in[5];
    const float* enc_wv   = (const float*)d_in[6];
    const float* enc_wo   = (const float*)d_in[7];
    const float* enc_ln1g = (const float*)d_in[8];
    const float* enc_ln1b = (const float*)d_in[9];
    const float* enc_w1   = (const float*)d_in[10];
    const float* enc_b1   = (const float*)d_in[11];
    const float* enc_w2   = (const float*)d_in[12];
    const float* enc_b2   = (const float*)d_in[13];
    const float* enc_ln2g = (const float*)d_in[14];
    const float* enc_ln2b = (const float*)d_in[15];
    const float* dec_wq   = (const float*)d_in[16];
    const float* dec_wk   = (const float*)d_in[17];
    const float* dec_wv   = (const float*)d_in[18];
    const float* dec_wo   = (const float*)d_in[19];
    const float* dec_ln1g = (const float*)d_in[20];
    const float* dec_ln1b = (const float*)d_in[21];
    const float* dec_cq   = (const float*)d_in[22];
    const float* dec_ck   = (const float*)d_in[23];
    const float* dec_cv   = (const float*)d_in[24];
    const float* dec_co   = (const float*)d_in[25];
    const float* dec_ln2g = (const float*)d_in[26];
    const float* dec_ln2b = (const float*)d_in[27];
    const float* dec_w1   = (const float*)d_in[28];
    const float* dec_b1   = (const float*)d_in[29];
    const float* dec_w2   = (const float*)d_in[30];
    const float* dec_b2   = (const float*)d_in[31];
    const float* dec_ln3g = (const float*)d_in[32];
    const float* dec_ln3b = (const float*)d_in[33];
    const float* proj     = (const float*)d_in[34];

    float* OUT = (float*)d_out;
    char* base = (char*)d_ws;

    size_t off = 0;
    auto carve = [&](size_t bytes) { char* p = base + off; off += (bytes + 255) & ~(size_t)255; return p; };

    float* X      = (float*)carve(MSZE * 4);
    float* Yb     = (float*)carve(MSZE * 4);
    u16*   Xb     = (u16*)  carve(MSZE * 2);
    u16*   Ybf    = (u16*)  carve(MSZE * 2);
    u16*   QKb    = (u16*)  carve((size_t)MTOK * 1024 * 2);
    u16*   Vt     = (u16*)  carve((size_t)512 * MTOK * 2);
    u16*   CTX    = (u16*)  carve(MSZE * 2);
    u16*   HFF    = (u16*)  carve((size_t)MTOK * FFN * 2);
    u16*   Kcr    = (u16*)  carve((size_t)NL * MTOK * 512 * 2);
    u16*   Vtc    = (u16*)  carve((size_t)NL * 512 * MTOK * 2);
    u16*   projT  = (u16*)  carve((size_t)NVOC * 512 * 2);
    float* Tp4    = (float*)carve((size_t)4 * MSZE * 4);       // split-K partials (shared)

    const size_t WFULL_B = (size_t)12 * WBLK * 2;
    bool full = (ws_size >= off + WFULL_B);
    u16* Wreg = (u16*)carve(full ? WFULL_B : (size_t)WBLK * 2);

    auto T = [&](const float* s, u16* d, int Kd, int Nd, size_t ss, size_t ds, int L) {
        transp<<<dim3(Nd / 64, Kd / 64, L), 256, 0, stream>>>(s, d, Nd, Kd, ss, ds);
    };

    // ---- one-time prep: transposes + projT + embeddings in a single launch ----
    if (full) {
        transp_all<<<dim3(18848), 256, 0, stream>>>(
            enc_wq, enc_wk, enc_wv, enc_wo,
            dec_wq, dec_wk, dec_wv, dec_wo,
            dec_cq, dec_ck, dec_cv, dec_co,
            enc_w1, dec_w1, enc_w2, dec_w2,
            proj, Wreg, projT,
            src, trg, emb_src, emb_trg, X, Xb, Yb, Ybf);
    } else {
        T(proj, projT, 512, NVOC, 0, 0, 1);
        embed_kernel<<<2 * MTOK, DDIM, 0, stream>>>(src, trg, emb_src, emb_trg, X, Xb, Yb, Ybf);
    }

    // self-attention: (QK-proj ∥ V^T-proj) dual 64² GEMM (768 blocks) + flash (256 blocks)
    //                 + O-proj split-K2 (512 blocks) -> Tp4[0..1]
    auto self_attn = [&](const u16* xsrc, const u16* wb, const int* mask_ids, int causal) {
        mgemm_dual<64, 64><<<dim3(768), 256, 0, stream>>>(
            xsrc, 512, wb + OFF_QK, 512, QKb, 1024, 16, 512,
            wb + OFF_WV, 512, xsrc, 512, Vt, MTOK, 32,
            512);
        if (causal)
            flash_attn<1><<<dim3(8, 32), 256, 0, stream>>>(QKb, 1024, QKb + 512, 1024, Vt, CTX, mask_ids);
        else
            flash_attn<0><<<dim3(8, 32), 256, 0, stream>>>(QKb, 1024, QKb + 512, 1024, Vt, CTX, mask_ids);
        mgemm<64, 64, 0, 0, 0><<<dim3(8, 32, 2), 256, 0, stream>>>(
            CTX, 512, 0, 256, wb + OFF_WO, 512, 0, 256, Tp4, 512, 0, MSZE, 256, nullptr);
    };

    auto o_proj_sk2 = [&](const u16* a, const u16* w) {
        mgemm<64, 64, 0, 0, 0><<<dim3(8, 32, 2), 256, 0, stream>>>(
            a, 512, 0, 256, w, 512, 0, 256, Tp4, 512, 0, MSZE, 256, nullptr);
    };

    // FFN: W1 64² (1024 blocks, relu+bias) then W2 split-K(4x512) 64² (1024 blocks) -> Tp4[0..3]
    auto ffn = [&](const u16* xsrc, const u16* wb, const float* b1) {
        mgemm<64, 64, 1, 1, 1><<<dim3(32, 32, 1), 256, 0, stream>>>(
            xsrc, 512, 0, 0, wb + OFF_W1, 512, 0, 0, HFF, FFN, 0, 0, 512, b1);
        mgemm<64, 64, 0, 0, 0><<<dim3(8, 32, 4), 256, 0, stream>>>(
            HFF, 2048, 0, 512, wb + OFF_W2, 2048, 0, 512,
            Tp4, 512, 0, MSZE, 512, nullptr);
    };

    const size_t M2 = M2CNT, MF1 = MF1CNT;

    // ---- encoder ----
    for (int l = 0; l < NL; l++) {
        u16* wb;
        if (full) wb = Wreg + (size_t)l * WBLK;
        else {
            wb = Wreg;
            T(enc_wq + l * M2,  wb + OFF_QK,      512, 512,  0, 0, 1);
            T(enc_wk + l * M2,  wb + OFF_QK + M2, 512, 512,  0, 0, 1);
            T(enc_wv + l * M2,  wb + OFF_WV,      512, 512,  0, 0, 1);
            T(enc_wo + l * M2,  wb + OFF_WO,      512, 512,  0, 0, 1);
            T(enc_w1 + l * MF1, wb + OFF_W1,      512, 2048, 0, 0, 1);
            T(enc_w2 + l * MF1, wb + OFF_W2,      2048, 512, 0, 0, 1);
        }
        self_attn(Xb, wb, src, 0);
        add_ln_rd<2, 0><<<MTOK, 256, 0, stream>>>(X, Tp4, nullptr,
            enc_ln1g + l * DDIM, enc_ln1b + l * DDIM, Xb);
        ffn(Xb, wb, enc_b1 + l * FFN);
        add_ln_rd<4, 1><<<MTOK, 256, 0, stream>>>(X, Tp4, enc_b2 + l * DDIM,
            enc_ln2g + l * DDIM, enc_ln2b + l * DDIM, Xb);
    }

    // ---- cross-attention K / V^T for all 6 decoder layers (single launch) ----
    if (full) {
        cross_kv<<<dim3(3072), 256, 0, stream>>>(Xb, Wreg + (size_t)NL * WBLK, Kcr, Vtc);
    }

    // ---- decoder ----
    for (int l = 0; l < NL; l++) {
        u16* wb;
        if (full) wb = Wreg + (size_t)(NL + l) * WBLK;
        else {
            wb = Wreg;
            T(dec_wq + l * M2,  wb + OFF_QK,      512, 512,  0, 0, 1);
            T(dec_wk + l * M2,  wb + OFF_QK + M2, 512, 512,  0, 0, 1);
            T(dec_wv + l * M2,  wb + OFF_WV,      512, 512,  0, 0, 1);
            T(dec_wo + l * M2,  wb + OFF_WO,      512, 512,  0, 0, 1);
            T(dec_cq + l * M2,  wb + OFF_CQ,      512, 512,  0, 0, 1);
            T(dec_ck + l * M2,  wb + OFF_CK,      512, 512,  0, 0, 1);
            T(dec_cv + l * M2,  wb + OFF_CV,      512, 512,  0, 0, 1);
            T(dec_co + l * M2,  wb + OFF_CO,      512, 512,  0, 0, 1);
            T(dec_w1 + l * MF1, wb + OFF_W1,      512, 2048, 0, 0, 1);
            T(dec_w2 + l * MF1, wb + OFF_W2,      2048, 512, 0, 0, 1);
            mgemm<64, 64, 1, 0, 0><<<dim3(8, 32, 1), 256, 0, stream>>>(
                Xb, 512, 0, 0, wb + OFF_CK, 512, 0, 0, Kcr + (size_t)l * MTOK * 512, 512, 0, 0, 512, nullptr);
            mgemm<64, 64, 1, 0, 0><<<dim3(32, 8, 1), 256, 0, stream>>>(
                wb + OFF_CV, 512, 0, 0, Xb, 512, 0, 0, Vtc + (size_t)l * 512 * MTOK, MTOK, 0, 0, 512, nullptr);
        }
        // masked self-attention (O-proj split-K2 -> Tp4)
        self_attn(Ybf, wb, trg, 1);
        add_ln_rd<2, 0><<<MTOK, 256, 0, stream>>>(Yb, Tp4, nullptr,
            dec_ln1g + l * DDIM, dec_ln1b + l * DDIM, Ybf);
        // cross-attention
        mgemm<64, 64, 1, 0, 0><<<dim3(8, 32, 1), 256, 0, stream>>>(
            Ybf, 512, 0, 0, wb + OFF_CQ, 512, 0, 0, QKb, 1024, 0, 0, 512, nullptr);
        flash_attn<0><<<dim3(8, 32), 256, 0, stream>>>(
            QKb, 1024, Kcr + (size_t)l * MTOK * 512, 512, Vtc + (size_t)l * 512 * MTOK, CTX, src);
        o_proj_sk2(CTX, wb + OFF_CO);
        add_ln_rd<2, 0><<<MTOK, 256, 0, stream>>>(Yb, Tp4, nullptr,
            dec_ln2g + l * DDIM, dec_ln2b + l * DDIM, Ybf);
        // FFN
        ffn(Ybf, wb, dec_b1 + l * FFN);
        add_ln_rd<4, 1><<<MTOK, 256, 0, stream>>>(Yb, Tp4, dec_b2 + l * DDIM,
            dec_ln3g + l * DDIM, dec_ln3b + l * DDIM, Ybf);
    }

    // ---- final vocab projection (128x128 tile, XCD-swizzled; 4000 blocks, 4000 % 8 == 0) ----
    mgemm<128, 128, 0, 0, 0, 1><<<dim3(NVOC / 128, MTOK / 128, 1), 256, 0, stream>>>(
        Ybf, 512, 0, 0, projT, 512, 0, 0, OUT, NVOC, 0, 0, 512, nullptr);
}

// Round 16
// 1395.583 us; speedup vs baseline: 1.0541x; 1.0258x over previous
//
#include <hip/hip_runtime.h>
#include <math.h>

// ---------------- problem constants ----------------
#define BBATCH 4
#define SS 512
#define DDIM 512
#define FFN 2048
#define NHEAD 8
#define DHEAD 64
#define NL 6
#define NVOC 32000
#define MTOK (BBATCH*SS)       // 2048
#define PAD_ID 0
#define MSZE ((size_t)MTOK * DDIM)   // 1,048,576 elements

typedef unsigned short u16;
typedef __attribute__((ext_vector_type(8))) short short8;   // 8 bf16 (4 VGPRs)
typedef __attribute__((ext_vector_type(4))) float f32x4;

__device__ __forceinline__ u16 f2bf(float f) {
    union { float f; unsigned u; } v; v.f = f;
    unsigned r = ((v.u >> 16) & 1u) + 0x7fffu;   // round-to-nearest-even
    return (u16)((v.u + r) >> 16);
}

__device__ __forceinline__ void gload16(const u16* g, u16* l) {
    __builtin_amdgcn_global_load_lds(
        (const __attribute__((address_space(1))) void*)g,
        (__attribute__((address_space(3))) void*)l, 16, 0, 0);
}

// counted vmcnt wait (literal-immediate) + scheduling fence (rule #18)
template<int N> __device__ __forceinline__ void waitv() {
    if constexpr (N == 0)       asm volatile("s_waitcnt vmcnt(0)" ::: "memory");
    else if constexpr (N == 2)  asm volatile("s_waitcnt vmcnt(2)" ::: "memory");
    else if constexpr (N == 4)  asm volatile("s_waitcnt vmcnt(4)" ::: "memory");
    else if constexpr (N == 6)  asm volatile("s_waitcnt vmcnt(6)" ::: "memory");
    else if constexpr (N == 8)  asm volatile("s_waitcnt vmcnt(8)" ::: "memory");
    else if constexpr (N == 12) asm volatile("s_waitcnt vmcnt(12)" ::: "memory");
    __builtin_amdgcn_sched_barrier(0);
}
__device__ __forceinline__ void rawbar() {
    __builtin_amdgcn_s_barrier();
    __builtin_amdgcn_sched_barrier(0);
}

// ======================= MFMA GEMM core (NT): C[M,N] = A[M,K] * B[N,K]^T =======================
// 4-slot LDS ring, 3 tiles in flight (counted vmcnt). 256 threads = 4 waves (2x2).
template<int BM, int BN, int OUTBF, int RELU, int BIAS>
__device__ __forceinline__ void gemm_core(
    u16* __restrict__ AsB, u16* __restrict__ BsB,     // 4*BM*32 / 4*BN*32
    const u16* __restrict__ A, int lda,
    const u16* __restrict__ B, int ldb,
    void* __restrict__ Cv, int ldc,
    int row0, int col0, int K, const float* __restrict__ bias)
{
    const int tid  = threadIdx.x;
    const int lane = tid & 63;
    const int wid  = tid >> 6;
    const int wr   = wid >> 1, wc = wid & 1;
    constexpr int MF = BM / 32, NF = BN / 32, RA = BM / 64, RB = BN / 64;
    constexpr int LPT = RA + RB;

    const u16* aSrc[RA]; int aOff[RA];
    #pragma unroll
    for (int r = 0; r < RA; r++) {
        int row = (tid >> 2) + r * 64;
        int slot = ((tid & 3) << 4) ^ ((row & 3) << 4);
        aSrc[r] = A + (size_t)(row0 + row) * lda + (slot >> 1);
        aOff[r] = r * 2048 + tid * 8;
    }
    const u16* bSrc[RB]; int bOff[RB];
    #pragma unroll
    for (int r = 0; r < RB; r++) {
        int row = (tid >> 2) + r * 64;
        int slot = ((tid & 3) << 4) ^ ((row & 3) << 4);
        bSrc[r] = B + (size_t)(col0 + row) * ldb + (slot >> 1);
        bOff[r] = r * 2048 + tid * 8;
    }

    f32x4 acc[MF][NF];
    const f32x4 zero = {0.f, 0.f, 0.f, 0.f};
    #pragma unroll
    for (int m = 0; m < MF; m++)
        #pragma unroll
        for (int n = 0; n < NF; n++) acc[m][n] = zero;

    auto issue = [&](int t) {
        u16* ad = AsB + (t & 3) * (BM * 32);
        u16* bd = BsB + (t & 3) * (BN * 32);
        #pragma unroll
        for (int r = 0; r < RA; r++) gload16(aSrc[r] + t * 32, ad + aOff[r]);
        #pragma unroll
        for (int r = 0; r < RB; r++) gload16(bSrc[r] + t * 32, bd + bOff[r]);
    };
    auto comp = [&](int t) {
        const u16* as = AsB + (t & 3) * (BM * 32);
        const u16* bs = BsB + (t & 3) * (BN * 32);
        short8 af[MF], bf[NF];
        #pragma unroll
        for (int m = 0; m < MF; m++) {
            int row = wr * (BM / 2) + m * 16 + (lane & 15);
            int slot = ((lane >> 4) << 4) ^ ((row & 3) << 4);
            af[m] = *(const short8*)&as[row * 32 + (slot >> 1)];
        }
        #pragma unroll
        for (int n = 0; n < NF; n++) {
            int row = wc * (BN / 2) + n * 16 + (lane & 15);
            int slot = ((lane >> 4) << 4) ^ ((row & 3) << 4);
            bf[n] = *(const short8*)&bs[row * 32 + (slot >> 1)];
        }
        __builtin_amdgcn_s_setprio(1);
        #pragma unroll
        for (int m = 0; m < MF; m++)
            #pragma unroll
            for (int n = 0; n < NF; n++)
                acc[m][n] = __builtin_amdgcn_mfma_f32_16x16x32_bf16(af[m], bf[n], acc[m][n], 0, 0, 0);
        __builtin_amdgcn_s_setprio(0);
    };

    const int nt = K / 32;
    issue(0); issue(1); issue(2);
    int t = 0;
    for (; t < nt - 2; ++t) {
        waitv<2 * LPT>();
        rawbar();
        if (t + 3 < nt) issue(t + 3);
        comp(t);
    }
    waitv<LPT>(); rawbar(); comp(nt - 2);
    waitv<0>();   rawbar(); comp(nt - 1);

    const int crow = row0 + wr * (BM / 2);
    const int ccol = col0 + wc * (BN / 2);
    #pragma unroll
    for (int m = 0; m < MF; m++) {
        #pragma unroll
        for (int n = 0; n < NF; n++) {
            int col = ccol + n * 16 + (lane & 15);
            float bv = BIAS ? bias[col] : 0.0f;
            #pragma unroll
            for (int i = 0; i < 4; i++) {
                int row = crow + m * 16 + ((lane >> 4) << 2) + i;
                float v = acc[m][n][i] + bv;
                if (RELU) v = fmaxf(v, 0.0f);
                if (OUTBF) ((u16*)Cv)[(size_t)row * ldc + col] = f2bf(v);
                else       ((float*)Cv)[(size_t)row * ldc + col] = v;
            }
        }
    }
}

// batched/swizzled wrapper (z: zb = z>>3 batch stride, zh = z&7 head/split stride)
template<int BM, int BN, int OUTBF, int RELU, int BIAS, int SWZ = 0>
__global__ __launch_bounds__(256) void mgemm(
    const u16* __restrict__ A, int lda, size_t aSb, size_t aSh,
    const u16* __restrict__ B, int ldb, size_t bSb, size_t bSh,
    void* __restrict__ Cv, int ldc, size_t cSb, size_t cSh,
    int K, const float* __restrict__ bias)
{
    __shared__ __align__(16) u16 As[4 * BM * 32];
    __shared__ __align__(16) u16 Bs[4 * BN * 32];
    int bx = blockIdx.x, by = blockIdx.y;
    if (SWZ) {
        int nwg = gridDim.x * gridDim.y;
        int lin = by * gridDim.x + bx;
        int cpx = nwg >> 3;
        int s = (lin & 7) * cpx + (lin >> 3);
        bx = s % gridDim.x; by = s / gridDim.x;
    }
    const int zb = blockIdx.z >> 3, zh = blockIdx.z & 7;
    const u16* Ab = A + (size_t)zb * aSb + (size_t)zh * aSh;
    const u16* Bb = B + (size_t)zb * bSb + (size_t)zh * bSh;
    void* Cb = OUTBF ? (void*)((u16*)Cv + (size_t)zb * cSb + (size_t)zh * cSh)
                     : (void*)((float*)Cv + (size_t)zb * cSb + (size_t)zh * cSh);
    gemm_core<BM, BN, OUTBF, RELU, BIAS>(As, Bs, Ab, lda, Bb, ldb, Cb, ldc,
                                          by * BM, bx * BN, K, bias);
}

// dual-job GEMM: two independent NT gemms in one launch (bf16 out; job1 may have relu/bias)
template<int BM, int BN, int RELU1 = 0, int BIAS1 = 0>
__global__ __launch_bounds__(256) void mgemm_dual(
    const u16* __restrict__ A1, int lda1, const u16* __restrict__ B1, int ldb1,
    u16* __restrict__ C1, int ldc1, int nx1, int nblk1,
    const u16* __restrict__ A2, int lda2, const u16* __restrict__ B2, int ldb2,
    u16* __restrict__ C2, int ldc2, int nx2,
    int K, const float* __restrict__ bias1)
{
    __shared__ __align__(16) u16 As[4 * BM * 32];
    __shared__ __align__(16) u16 Bs[4 * BN * 32];
    int id = blockIdx.x;
    if (id < nblk1) {
        gemm_core<BM, BN, 1, RELU1, BIAS1>(As, Bs, A1, lda1, B1, ldb1, C1, ldc1,
                                            (id / nx1) * BM, (id % nx1) * BN, K, bias1);
    } else {
        id -= nblk1;
        gemm_core<BM, BN, 1, 0, 0>(As, Bs, A2, lda2, B2, ldb2, C2, ldc2,
                                    (id / nx2) * BM, (id % nx2) * BN, K, nullptr);
    }
}

// ---- weight-block layout (u16 offsets) ----
#define OFF_QK 0u
#define OFF_WV 524288u
#define OFF_WO 786432u
#define OFF_CQ 1048576u
#define OFF_CK 1310720u
#define OFF_CV 1572864u
#define OFF_CO 1835008u
#define OFF_W1 2097152u
#define OFF_W2 3145728u
#define WBLK   4194304u
#define M2CNT  262144u
#define MF1CNT 1048576u

// quad QKV: enc QK|V + dec-L0 QK|V in ONE launch (1536 blocks)
__global__ __launch_bounds__(256) void qkv_quad(
    const u16* __restrict__ Xb, const u16* __restrict__ Ybf,
    const u16* __restrict__ We, const u16* __restrict__ Wd0,
    u16* __restrict__ QKb, u16* __restrict__ Vt,
    u16* __restrict__ QKb2, u16* __restrict__ Vt2)
{
    __shared__ __align__(16) u16 As[4 * 64 * 32];
    __shared__ __align__(16) u16 Bs[4 * 64 * 32];
    int id = blockIdx.x;
    if (id < 512)
        gemm_core<64,64,1,0,0>(As, Bs, Xb, 512, We + OFF_QK, 512, QKb, 1024,
                               (id >> 4) * 64, (id & 15) * 64, 512, nullptr);
    else if (id < 768) {
        int t = id - 512;
        gemm_core<64,64,1,0,0>(As, Bs, We + OFF_WV, 512, Xb, 512, Vt, MTOK,
                               (t >> 5) * 64, (t & 31) * 64, 512, nullptr);
    } else if (id < 1280) {
        int t = id - 768;
        gemm_core<64,64,1,0,0>(As, Bs, Ybf, 512, Wd0 + OFF_QK, 512, QKb2, 1024,
                               (t >> 4) * 64, (t & 15) * 64, 512, nullptr);
    } else {
        int t = id - 1280;
        gemm_core<64,64,1,0,0>(As, Bs, Wd0 + OFF_WV, 512, Ybf, 512, Vt2, MTOK,
                               (t >> 5) * 64, (t & 31) * 64, 512, nullptr);
    }
}

// paired O-proj (split-K2 each): enc CTX*Wo -> Tp4[0..1], dec CTX2*Wo_d0 -> Tp4[2..3]
__global__ __launch_bounds__(256) void oproj_pair(
    const u16* __restrict__ CTX, const u16* __restrict__ We,
    const u16* __restrict__ CTX2, const u16* __restrict__ Wd0,
    float* __restrict__ Tp4)
{
    __shared__ __align__(16) u16 As[4 * 64 * 32];
    __shared__ __align__(16) u16 Bs[4 * 64 * 32];
    int id = blockIdx.x;
    int which = id >> 9;
    int kh = (id >> 8) & 1;
    int t = id & 255;
    const u16* A = (which ? CTX2 : CTX) + kh * 256;
    const u16* W = (which ? Wd0 + OFF_WO : We + OFF_WO) + kh * 256;
    float* out = Tp4 + (size_t)(which * 2 + kh) * MSZE;
    gemm_core<64,64,0,0,0>(As, Bs, A, 512, W, 512, out, 512,
                           (t >> 3) * 64, (t & 7) * 64, 256, nullptr);
}

// cross-attention K-proj + V^T-proj for all 6 decoder layers in ONE launch (3072 blocks)
__global__ __launch_bounds__(256) void cross_kv(
    const u16* __restrict__ Xb, const u16* __restrict__ Wd,
    u16* __restrict__ Kcr, u16* __restrict__ Vtc)
{
    __shared__ __align__(16) u16 As[4 * 64 * 32];
    __shared__ __align__(16) u16 Bs[4 * 64 * 32];
    int id = blockIdx.x;
    if (id < 1536) {
        int l = id >> 8, t = id & 255;
        const u16* w = Wd + (size_t)l * WBLK + OFF_CK;
        gemm_core<64, 64, 1, 0, 0>(As, Bs, Xb, 512, w, 512,
            Kcr + (size_t)l * MTOK * 512, 512, (t >> 3) * 64, (t & 7) * 64, 512, nullptr);
    } else {
        id -= 1536;
        int l = id >> 8, t = id & 255;
        const u16* w = Wd + (size_t)l * WBLK + OFF_CV;
        gemm_core<64, 64, 1, 0, 0>(As, Bs, w, 512, Xb, 512,
            Vtc + (size_t)l * 512 * MTOK, MTOK, (t >> 5) * 64, (t & 31) * 64, 512, nullptr);
    }
}

// ======================= flash attention body (QBLK=64, 4 waves, 3-slot counted-vmcnt ring) =======================
// smem layout: Kl 3*4096 u16 | Vl 3*4096 u16 | Pl 4*1024 u16 | msk 512 f32  (59392 B)
__device__ __forceinline__ void flash_body(char* smem, int causal, int qt, int bh,
    const u16* __restrict__ Qp, int ldq,
    const u16* __restrict__ Kp, int ldk,
    const u16* __restrict__ Vtp,
    u16* __restrict__ O, const int* __restrict__ ids)
{
    u16* Kl = (u16*)smem;
    u16* Vl = Kl + 12288;
    u16* Pl = Vl + 12288;
    float* msk = (float*)(Pl + 4096);

    const int tid = threadIdx.x, lane = tid & 63, wid = tid >> 6;
    const int b = bh >> 3, h = bh & 7;
    const int q0 = qt * 64;

    for (int i = tid; i < SS; i += 256)
        msk[i] = (ids[b * SS + i] == PAD_ID) ? -1e30f : 0.0f;

    const int qloc = wid * 16 + (lane & 15);
    const u16* Qb = Qp + (size_t)(b * SS + q0 + qloc) * ldq + h * 64 + ((lane >> 4) * 8);
    short8 qf[2];
    qf[0] = *(const short8*)(Qb);
    qf[1] = *(const short8*)(Qb + 32);

    const u16* Kb = Kp + (size_t)b * SS * ldk + h * 64;
    const u16* Vb = Vtp + (size_t)(h * 64) * MTOK + b * SS;

    auto stage = [&](int buf, int kt) {
        int row = tid >> 3, sl = tid & 7;
        #pragma unroll
        for (int r = 0; r < 2; r++) {
            int rr = row + r * 32;
            int ls = sl ^ (rr & 7);
            gload16(Kb + (size_t)(kt * 64 + rr) * ldk + ls * 8, &Kl[buf * 4096 + rr * 64 + sl * 8]);
            gload16(Vb + (size_t)rr * MTOK + kt * 64 + ls * 8, &Vl[buf * 4096 + rr * 64 + sl * 8]);
        }
    };

    const int nt = causal ? (qt + 1) : (SS / 64);

    float m_i[4], l_i[4];
    f32x4 o_acc[4];
    const f32x4 zero = {0.f, 0.f, 0.f, 0.f};
    #pragma unroll
    for (int i = 0; i < 4; i++) { m_i[i] = -1e30f; l_i[i] = 0.0f; }
    #pragma unroll
    for (int n = 0; n < 4; n++) o_acc[n] = zero;

    auto comp = [&](int kt) {
        const int cur = kt % 3;
        f32x4 s_acc[4];
        #pragma unroll
        for (int n = 0; n < 4; n++) s_acc[n] = zero;
        __builtin_amdgcn_s_setprio(1);
        #pragma unroll
        for (int kk = 0; kk < 2; kk++) {
            #pragma unroll
            for (int n = 0; n < 4; n++) {
                int row = n * 16 + (lane & 15);
                int ls = (kk * 4 + (lane >> 4)) ^ (row & 7);
                short8 kf = *(const short8*)&Kl[cur * 4096 + row * 64 + ls * 8];
                s_acc[n] = __builtin_amdgcn_mfma_f32_16x16x32_bf16(qf[kk], kf, s_acc[n], 0, 0, 0);
            }
        }
        __builtin_amdgcn_s_setprio(0);

        float sv[4][4];
        #pragma unroll
        for (int n = 0; n < 4; n++) {
            int kg = kt * 64 + n * 16 + (lane & 15);
            float mk = msk[kg];
            #pragma unroll
            for (int i = 0; i < 4; i++) {
                float s = s_acc[n][i] * 0.125f + mk;
                if (causal) {
                    int qg = q0 + wid * 16 + ((lane >> 4) << 2) + i;
                    if (kg > qg) s = -1e30f;
                }
                sv[n][i] = s;
            }
        }
        float pm[4], mn[4], rs[4], ps[4];
        #pragma unroll
        for (int i = 0; i < 4; i++)
            pm[i] = fmaxf(fmaxf(sv[0][i], sv[1][i]), fmaxf(sv[2][i], sv[3][i]));
        #pragma unroll
        for (int i = 0; i < 4; i++) {
            #pragma unroll
            for (int msh = 1; msh <= 8; msh <<= 1)
                pm[i] = fmaxf(pm[i], __shfl_xor(pm[i], msh));
            mn[i] = fmaxf(m_i[i], pm[i]);
            rs[i] = __expf(m_i[i] - mn[i]);
            m_i[i] = mn[i];
        }
        float p[4][4];
        #pragma unroll
        for (int n = 0; n < 4; n++)
            #pragma unroll
            for (int i = 0; i < 4; i++)
                p[n][i] = (sv[n][i] < -1e29f) ? 0.0f : __expf(sv[n][i] - mn[i]);
        #pragma unroll
        for (int i = 0; i < 4; i++) {
            ps[i] = p[0][i] + p[1][i] + p[2][i] + p[3][i];
            #pragma unroll
            for (int msh = 1; msh <= 8; msh <<= 1)
                ps[i] += __shfl_xor(ps[i], msh);
            l_i[i] = l_i[i] * rs[i] + ps[i];
        }
        #pragma unroll
        for (int n = 0; n < 4; n++)
            #pragma unroll
            for (int i = 0; i < 4; i++)
                o_acc[n][i] *= rs[i];

        #pragma unroll
        for (int n = 0; n < 4; n++) {
            int k = n * 16 + (lane & 15);
            #pragma unroll
            for (int i = 0; i < 4; i++) {
                int q = ((lane >> 4) << 2) + i;
                Pl[wid * 1024 + q * 64 + (((k >> 3) ^ (q & 7)) << 3) + (k & 7)] = f2bf(p[n][i]);
            }
        }
        asm volatile("s_waitcnt lgkmcnt(0)" ::: "memory");
        __builtin_amdgcn_sched_barrier(0);

        __builtin_amdgcn_s_setprio(1);
        #pragma unroll
        for (int kk = 0; kk < 2; kk++) {
            int qrow = lane & 15;
            int lsp = (kk * 4 + (lane >> 4)) ^ (qrow & 7);
            short8 pa = *(const short8*)&Pl[wid * 1024 + qrow * 64 + lsp * 8];
            #pragma unroll
            for (int nf = 0; nf < 4; nf++) {
                int row = nf * 16 + (lane & 15);
                int vs = (kk * 4 + (lane >> 4)) ^ (row & 7);
                short8 vf = *(const short8*)&Vl[cur * 4096 + row * 64 + vs * 8];
                o_acc[nf] = __builtin_amdgcn_mfma_f32_16x16x32_bf16(pa, vf, o_acc[nf], 0, 0, 0);
            }
        }
        __builtin_amdgcn_s_setprio(0);
    };

    stage(0, 0);
    stage(1, 1);
    int t = 0;
    for (; t < nt - 1; ++t) {
        waitv<4>();
        rawbar();
        if (t + 2 < nt) stage((t + 2) % 3, t + 2);
        comp(t);
    }
    waitv<0>(); rawbar(); comp(nt - 1);

    #pragma unroll
    for (int nf = 0; nf < 4; nf++) {
        int d = h * 64 + nf * 16 + (lane & 15);
        #pragma unroll
        for (int i = 0; i < 4; i++) {
            int qg = b * SS + q0 + wid * 16 + ((lane >> 4) << 2) + i;
            O[(size_t)qg * DDIM + d] = f2bf(o_acc[nf][i] / l_i[i]);
        }
    }
}

template<int CAUSAL>
__global__ __launch_bounds__(256) void flash_attn(
    const u16* __restrict__ Qp, int ldq,
    const u16* __restrict__ Kp, int ldk,
    const u16* __restrict__ Vtp,
    u16* __restrict__ O,
    const int* __restrict__ ids)
{
    __shared__ __align__(16) char smem[59392];
    flash_body(smem, CAUSAL, blockIdx.x, blockIdx.y, Qp, ldq, Kp, ldk, Vtp, O, ids);
}

// enc non-causal (y<32) + dec-L0 causal (y>=32) in one launch
__global__ __launch_bounds__(256) void flash_pair(
    const u16* __restrict__ QKb, const u16* __restrict__ Vt, u16* __restrict__ CTX,
    const int* __restrict__ src,
    const u16* __restrict__ QKb2, const u16* __restrict__ Vt2, u16* __restrict__ CTX2,
    const int* __restrict__ trg)
{
    __shared__ __align__(16) char smem[59392];
    if (blockIdx.y < 32)
        flash_body(smem, 0, blockIdx.x, blockIdx.y, QKb, 1024, QKb + 512, 1024, Vt, CTX, src);
    else
        flash_body(smem, 1, blockIdx.x, blockIdx.y - 32, QKb2, 1024, QKb2 + 512, 1024, Vt2, CTX2, trg);
}

// ============ transpose + convert core: dst[N,K] = bf16(src[K,N]) (64x64 tile) ============
__device__ __forceinline__ void transp_core(const float* __restrict__ src, u16* __restrict__ dst,
                                            int N, int K, int n0, int k0)
{
    __shared__ u16 t[64][65];
    const int tid = threadIdx.x;
    #pragma unroll
    for (int i = 0; i < 16; i++) {
        int idx = tid + i * 256;
        int kr = idx >> 6, nc = idx & 63;
        t[kr][nc] = f2bf(src[(size_t)(k0 + kr) * N + n0 + nc]);
    }
    __syncthreads();
    #pragma unroll
    for (int i = 0; i < 16; i++) {
        int idx = tid + i * 256;
        int nr = idx >> 6, kc = idx & 63;
        dst[(size_t)(n0 + nr) * K + k0 + kc] = t[kc][nr];
    }
}

__global__ __launch_bounds__(256) void transp(const float* __restrict__ src, u16* __restrict__ dst,
                                              int N, int K, size_t sStride, size_t dStride)
{
    transp_core(src + (size_t)blockIdx.z * sStride, dst + (size_t)blockIdx.z * dStride,
                N, K, blockIdx.x * 64, blockIdx.y * 64);
}

// ======== mega-prep: all weight transposes + vocab projT + BOTH embeddings in ONE launch ========
__global__ __launch_bounds__(256) void transp_all(
    const float* p0, const float* p1, const float* p2, const float* p3,
    const float* p4, const float* p5, const float* p6, const float* p7,
    const float* p8, const float* p9, const float* p10, const float* p11,
    const float* ew1, const float* dw1, const float* ew2, const float* dw2,
    const float* proj, u16* __restrict__ wreg, u16* __restrict__ projT,
    const int* __restrict__ src, const int* __restrict__ trg,
    const float* __restrict__ es, const float* __restrict__ et,
    float* __restrict__ X, u16* __restrict__ Xb,
    float* __restrict__ Y, u16* __restrict__ Ybf)
{
    int jid = blockIdx.x;
    if (jid < 4608) {
        int z = jid >> 6, t = jid & 63;
        int w = z % 12, l = z / 12;
        const float* ptrs[12] = {p0,p1,p2,p3,p4,p5,p6,p7,p8,p9,p10,p11};
        const float* srcw = ptrs[w] + (size_t)l * M2CNT;
        u16* dst = wreg + (w < 4 ? (size_t)l * WBLK + (size_t)w * M2CNT
                                 : (size_t)(NL + l) * WBLK + (size_t)(w - 4) * M2CNT);
        transp_core(srcw, dst, 512, 512, (t & 7) * 64, (t >> 3) * 64);
    } else if (jid < 7680) {
        int j = jid - 4608;
        int z = j >> 8, t = j & 255;
        int l = z % NL, w = z / NL;
        const float* srcw = (w ? dw1 : ew1) + (size_t)l * MF1CNT;
        u16* dst = wreg + (size_t)(w * NL + l) * WBLK + OFF_W1;
        transp_core(srcw, dst, 2048, 512, (t % 32) * 64, (t / 32) * 64);
    } else if (jid < 10752) {
        int j = jid - 7680;
        int z = j >> 8, t = j & 255;
        int l = z % NL, w = z / NL;
        const float* srcw = (w ? dw2 : ew2) + (size_t)l * MF1CNT;
        u16* dst = wreg + (size_t)(w * NL + l) * WBLK + OFF_W2;
        transp_core(srcw, dst, 512, 2048, (t % 8) * 64, (t / 8) * 64);
    } else if (jid < 14752) {
        int j = jid - 10752;
        transp_core(proj, projT, NVOC, 512, (j % 500) * 64, (j / 500) * 64);
    } else {
        int tok = jid - 14752;                 // 0..4095
        bool dec = tok >= MTOK;
        int tk = dec ? tok - MTOK : tok;
        int pos = tk & (SS - 1);
        int id2 = (dec ? trg : src)[tk];
        const float* emb = dec ? et : es;
        float* xo = dec ? Y : X;
        u16*   bo = dec ? Ybf : Xb;
        #pragma unroll
        for (int half = 0; half < 2; half++) {
            int d = threadIdx.x + half * 256;
            int i = d >> 1;
            double freq = exp(-(2.0 * (double)i / (double)DDIM) * log(10000.0));
            double ang = (double)pos * freq;
            float pe = (float)((d & 1) ? cos(ang) : sin(ang));
            float val = emb[(size_t)id2 * DDIM + d] * 22.62741699796952f + pe;
            xo[(size_t)tk * DDIM + d] = val;
            bo[(size_t)tk * DDIM + d] = f2bf(val);
        }
    }
}

// ============ merged embedding (fallback for !full path) ============
__global__ void embed_kernel(const int* __restrict__ src, const int* __restrict__ trg,
                             const float* __restrict__ es, const float* __restrict__ et,
                             float* __restrict__ X, u16* __restrict__ Xb,
                             float* __restrict__ Y, u16* __restrict__ Ybf)
{
    int gtok = blockIdx.x;
    int d = threadIdx.x;
    bool dec = gtok >= MTOK;
    int tok = dec ? gtok - MTOK : gtok;
    int pos = tok & (SS - 1);
    int id = (dec ? trg : src)[tok];
    const float* emb = dec ? et : es;
    int i = d >> 1;
    double freq = exp(-(2.0 * (double)i / (double)DDIM) * log(10000.0));
    double ang = (double)pos * freq;
    float pe = (float)((d & 1) ? cos(ang) : sin(ang));
    float val = emb[(size_t)id * DDIM + d] * 22.62741699796952f + pe;
    (dec ? Y : X)[(size_t)tok * DDIM + d] = val;
    (dec ? Ybf : Xb)[(size_t)tok * DDIM + d] = f2bf(val);
}

// ============ LN bodies ============
__device__ __forceinline__ void ln2_body(float* __restrict__ x, const float* __restrict__ part,
    const float* __restrict__ g, const float* __restrict__ bta, u16* __restrict__ xb, int row)
{
    int tid = threadIdx.x;
    size_t base = (size_t)row * DDIM;
    __shared__ float sbuf[4];

    float v0 = x[base + tid]       + part[base + tid]       + part[MSZE + base + tid];
    float v1 = x[base + tid + 256] + part[base + tid + 256] + part[MSZE + base + tid + 256];

    float s = v0 + v1;
    #pragma unroll
    for (int o = 32; o > 0; o >>= 1) s += __shfl_down(s, o);
    if ((tid & 63) == 0) sbuf[tid >> 6] = s;
    __syncthreads();
    float mean = (sbuf[0] + sbuf[1] + sbuf[2] + sbuf[3]) * (1.0f / DDIM);
    __syncthreads();

    float d0 = v0 - mean, d1 = v1 - mean;
    float ss = d0 * d0 + d1 * d1;
    #pragma unroll
    for (int o = 32; o > 0; o >>= 1) ss += __shfl_down(ss, o);
    if ((tid & 63) == 0) sbuf[tid >> 6] = ss;
    __syncthreads();
    float var = (sbuf[0] + sbuf[1] + sbuf[2] + sbuf[3]) * (1.0f / DDIM);
    float inv = rsqrtf(var + 1e-5f);

    float o0 = d0 * inv * g[tid]       + bta[tid];
    float o1 = d1 * inv * g[tid + 256] + bta[tid + 256];
    x[base + tid] = o0;
    x[base + tid + 256] = o1;
    xb[base + tid] = f2bf(o0);
    xb[base + tid + 256] = f2bf(o1);
}

// NP-way split-K reducer (+opt bias) + residual add + LayerNorm
template<int NP, int BIAS>
__global__ __launch_bounds__(256) void add_ln_rd(float* __restrict__ x,
    const float* __restrict__ part, const float* __restrict__ bias,
    const float* __restrict__ g, const float* __restrict__ bta, u16* __restrict__ xb)
{
    int row = blockIdx.x;
    int tid = threadIdx.x;
    size_t base = (size_t)row * DDIM;
    __shared__ float sbuf[4];

    float v0 = x[base + tid]       + (BIAS ? bias[tid] : 0.0f);
    float v1 = x[base + tid + 256] + (BIAS ? bias[tid + 256] : 0.0f);
    #pragma unroll
    for (int s4 = 0; s4 < NP; s4++) {
        v0 += part[s4 * MSZE + base + tid];
        v1 += part[s4 * MSZE + base + tid + 256];
    }

    float s = v0 + v1;
    #pragma unroll
    for (int o = 32; o > 0; o >>= 1) s += __shfl_down(s, o);
    if ((tid & 63) == 0) sbuf[tid >> 6] = s;
    __syncthreads();
    float mean = (sbuf[0] + sbuf[1] + sbuf[2] + sbuf[3]) * (1.0f / DDIM);
    __syncthreads();

    float d0 = v0 - mean, d1 = v1 - mean;
    float ss = d0 * d0 + d1 * d1;
    #pragma unroll
    for (int o = 32; o > 0; o >>= 1) ss += __shfl_down(ss, o);
    if ((tid & 63) == 0) sbuf[tid >> 6] = ss;
    __syncthreads();
    float var = (sbuf[0] + sbuf[1] + sbuf[2] + sbuf[3]) * (1.0f / DDIM);
    float inv = rsqrtf(var + 1e-5f);

    float o0 = d0 * inv * g[tid]       + bta[tid];
    float o1 = d1 * inv * g[tid + 256] + bta[tid + 256];
    x[base + tid] = o0;
    x[base + tid + 256] = o1;
    xb[base + tid] = f2bf(o0);
    xb[base + tid + 256] = f2bf(o1);
}

// paired LN: rows [0,2048) enc (X, Tp4[0..1]), rows [2048,4096) dec (Y, Tp4[2..3])
__global__ __launch_bounds__(256) void add_ln_pair(
    float* __restrict__ X, u16* __restrict__ Xb,
    const float* __restrict__ eg, const float* __restrict__ eb,
    float* __restrict__ Y, u16* __restrict__ Ybf,
    const float* __restrict__ dg, const float* __restrict__ db,
    const float* __restrict__ Tp4)
{
    int row = blockIdx.x;
    if (row < MTOK) ln2_body(X, Tp4, eg, eb, Xb, row);
    else            ln2_body(Y, Tp4 + 2 * MSZE, dg, db, Ybf, row - MTOK);
}

// ======================= host orchestration =======================
extern "C" void kernel_launch(void* const* d_in, const int* in_sizes, int n_in,
                              void* d_out, int out_size, void* d_ws, size_t ws_size,
                              hipStream_t stream)
{
    (void)in_sizes; (void)n_in; (void)out_size;

    const int*   src      = (const int*)  d_in[0];
    const int*   trg      = (const int*)  d_in[1];
    const float* emb_src  = (const float*)d_in[2];
    const float* emb_trg  = (const float*)d_in[3];
    const float* enc_wq   = (const float*)d_in[4];
    const float* enc_wk   = (const float*)d_in[5];
    const float* enc_wv   = (const float*)d_in[6];
    const float* enc_wo   = (const float*)d_in[7];
    const float* enc_ln1g = (const float*)d_in[8];
    const float* enc_ln1b = (const float*)d_in[9];
    const float* enc_w1   = (const float*)d_in[10];
    const float* enc_b1   = (const float*)d_in[11];
    const float* enc_w2   = (const float*)d_in[12];
    const float* enc_b2   = (const float*)d_in[13];
    const float* enc_ln2g = (const float*)d_in[14];
    const float* enc_ln2b = (const float*)d_in[15];
    const float* dec_wq   = (const float*)d_in[16];
    const float* dec_wk   = (const float*)d_in[17];
    const float* dec_wv   = (const float*)d_in[18];
    const float* dec_wo   = (const float*)d_in[19];
    const float* dec_ln1g = (const float*)d_in[20];
    const float* dec_ln1b = (const float*)d_in[21];
    const float* dec_cq   = (const float*)d_in[22];
    const float* dec_ck   = (const float*)d_in[23];
    const float* dec_cv   = (const float*)d_in[24];
    const float* dec_co   = (const float*)d_in[25];
    const float* dec_ln2g = (const float*)d_in[26];
    const float* dec_ln2b = (const float*)d_in[27];
    const float* dec_w1   = (const float*)d_in[28];
    const float* dec_b1   = (const float*)d_in[29];
    const float* dec_w2   = (const float*)d_in[30];
    const float* dec_b2   = (const float*)d_in[31];
    const float* dec_ln3g = (const float*)d_in[32];
    const float* dec_ln3b = (const float*)d_in[33];
    const float* proj     = (const float*)d_in[34];

    float* OUT = (float*)d_out;
    char* base = (char*)d_ws;

    size_t off = 0;
    auto carve = [&](size_t bytes) { char* p = base + off; off += (bytes + 255) & ~(size_t)255; return p; };

    float* X      = (float*)carve(MSZE * 4);
    float* Yb     = (float*)carve(MSZE * 4);
    u16*   Xb     = (u16*)  carve(MSZE * 2);
    u16*   Ybf    = (u16*)  carve(MSZE * 2);
    u16*   QKb    = (u16*)  carve((size_t)MTOK * 1024 * 2);
    u16*   QKb2   = (u16*)  carve((size_t)MTOK * 1024 * 2);
    u16*   Vt     = (u16*)  carve((size_t)512 * MTOK * 2);
    u16*   Vt2    = (u16*)  carve((size_t)512 * MTOK * 2);
    u16*   CTX    = (u16*)  carve(MSZE * 2);
    u16*   CTX2   = (u16*)  carve(MSZE * 2);
    u16*   HFF    = (u16*)  carve((size_t)MTOK * FFN * 2);
    u16*   Kcr    = (u16*)  carve((size_t)NL * MTOK * 512 * 2);
    u16*   Vtc    = (u16*)  carve((size_t)NL * 512 * MTOK * 2);
    u16*   projT  = (u16*)  carve((size_t)NVOC * 512 * 2);
    float* Tp4    = (float*)carve((size_t)4 * MSZE * 4);       // split-K partials (shared)

    const size_t WFULL_B = (size_t)12 * WBLK * 2;
    bool full = (ws_size >= off + WFULL_B);
    u16* Wreg = (u16*)carve(full ? WFULL_B : (size_t)WBLK * 2);

    auto T = [&](const float* s, u16* d, int Kd, int Nd, size_t ss, size_t ds, int L) {
        transp<<<dim3(Nd / 64, Kd / 64, L), 256, 0, stream>>>(s, d, Nd, Kd, ss, ds);
    };

    // ---- one-time prep: transposes + projT + embeddings in a single launch ----
    if (full) {
        transp_all<<<dim3(18848), 256, 0, stream>>>(
            enc_wq, enc_wk, enc_wv, enc_wo,
            dec_wq, dec_wk, dec_wv, dec_wo,
            dec_cq, dec_ck, dec_cv, dec_co,
            enc_w1, dec_w1, enc_w2, dec_w2,
            proj, Wreg, projT,
            src, trg, emb_src, emb_trg, X, Xb, Yb, Ybf);
    } else {
        T(proj, projT, 512, NVOC, 0, 0, 1);
        embed_kernel<<<2 * MTOK, DDIM, 0, stream>>>(src, trg, emb_src, emb_trg, X, Xb, Yb, Ybf);
    }

    // self-attention: QKV dual + flash + O-proj split-K2 -> Tp4[0..1]
    auto self_attn = [&](const u16* xsrc, const u16* wb, const int* mask_ids, int causal) {
        mgemm_dual<64, 64><<<dim3(768), 256, 0, stream>>>(
            xsrc, 512, wb + OFF_QK, 512, QKb, 1024, 16, 512,
            wb + OFF_WV, 512, xsrc, 512, Vt, MTOK, 32,
            512, nullptr);
        if (causal)
            flash_attn<1><<<dim3(8, 32), 256, 0, stream>>>(QKb, 1024, QKb + 512, 1024, Vt, CTX, mask_ids);
        else
            flash_attn<0><<<dim3(8, 32), 256, 0, stream>>>(QKb, 1024, QKb + 512, 1024, Vt, CTX, mask_ids);
        mgemm<64, 64, 0, 0, 0><<<dim3(8, 32, 2), 256, 0, stream>>>(
            CTX, 512, 0, 256, wb + OFF_WO, 512, 0, 256, Tp4, 512, 0, MSZE, 256, nullptr);
    };

    auto o_proj_sk2 = [&](const u16* a, const u16* w) {
        mgemm<64, 64, 0, 0, 0><<<dim3(8, 32, 2), 256, 0, stream>>>(
            a, 512, 0, 256, w, 512, 0, 256, Tp4, 512, 0, MSZE, 256, nullptr);
    };

    auto ffn = [&](const u16* xsrc, const u16* wb, const float* b1) {
        mgemm<64, 64, 1, 1, 1><<<dim3(32, 32, 1), 256, 0, stream>>>(
            xsrc, 512, 0, 0, wb + OFF_W1, 512, 0, 0, HFF, FFN, 0, 0, 512, b1);
        mgemm<64, 64, 0, 0, 0><<<dim3(8, 32, 4), 256, 0, stream>>>(
            HFF, 2048, 0, 512, wb + OFF_W2, 2048, 0, 512,
            Tp4, 512, 0, MSZE, 512, nullptr);
    };

    const size_t M2 = M2CNT, MF1 = MF1CNT;
    u16* Wd0 = Wreg + (size_t)NL * WBLK;     // dec layer-0 weight block (full mode)

    // ---- merged encoder-L0 front + decoder-L0 self-attention front (full mode) ----
    if (full) {
        u16* we = Wreg;                       // enc layer 0
        qkv_quad<<<dim3(1536), 256, 0, stream>>>(Xb, Ybf, we, Wd0, QKb, Vt, QKb2, Vt2);
        flash_pair<<<dim3(8, 64), 256, 0, stream>>>(QKb, Vt, CTX, src, QKb2, Vt2, CTX2, trg);
        oproj_pair<<<dim3(1024), 256, 0, stream>>>(CTX, we, CTX2, Wd0, Tp4);
        add_ln_pair<<<dim3(2 * MTOK), 256, 0, stream>>>(
            X, Xb, enc_ln1g, enc_ln1b, Yb, Ybf, dec_ln1g, dec_ln1b, Tp4);
        // enc FFN1 (relu+bias) || dec-L0 cross-Q proj (into QKb2 cols 0..511)
        mgemm_dual<64, 64, 1, 1><<<dim3(1280), 256, 0, stream>>>(
            Xb, 512, we + OFF_W1, 512, HFF, FFN, 32, 1024,
            Ybf, 512, Wd0 + OFF_CQ, 512, QKb2, 1024, 8,
            512, enc_b1);
        // enc FFN2 + LN2
        mgemm<64, 64, 0, 0, 0><<<dim3(8, 32, 4), 256, 0, stream>>>(
            HFF, 2048, 0, 512, we + OFF_W2, 2048, 0, 512,
            Tp4, 512, 0, MSZE, 512, nullptr);
        add_ln_rd<4, 1><<<MTOK, 256, 0, stream>>>(X, Tp4, enc_b2,
            enc_ln2g, enc_ln2b, Xb);
    }

    // ---- encoder layers (l=0 only in !full mode) ----
    for (int l = full ? 1 : 0; l < NL; l++) {
        u16* wb;
        if (full) wb = Wreg + (size_t)l * WBLK;
        else {
            wb = Wreg;
            T(enc_wq + l * M2,  wb + OFF_QK,      512, 512,  0, 0, 1);
            T(enc_wk + l * M2,  wb + OFF_QK + M2, 512, 512,  0, 0, 1);
            T(enc_wv + l * M2,  wb + OFF_WV,      512, 512,  0, 0, 1);
            T(enc_wo + l * M2,  wb + OFF_WO,      512, 512,  0, 0, 1);
            T(enc_w1 + l * MF1, wb + OFF_W1,      512, 2048, 0, 0, 1);
            T(enc_w2 + l * MF1, wb + OFF_W2,      2048, 512, 0, 0, 1);
        }
        self_attn(Xb, wb, src, 0);
        add_ln_rd<2, 0><<<MTOK, 256, 0, stream>>>(X, Tp4, nullptr,
            enc_ln1g + l * DDIM, enc_ln1b + l * DDIM, Xb);
        ffn(Xb, wb, enc_b1 + l * FFN);
        add_ln_rd<4, 1><<<MTOK, 256, 0, stream>>>(X, Tp4, enc_b2 + l * DDIM,
            enc_ln2g + l * DDIM, enc_ln2b + l * DDIM, Xb);
    }

    // ---- cross-attention K / V^T for all 6 decoder layers (single launch) ----
    if (full) {
        cross_kv<<<dim3(3072), 256, 0, stream>>>(Xb, Wd0, Kcr, Vtc);
    }

    // ---- decoder ----
    for (int l = 0; l < NL; l++) {
        u16* wb;
        if (full) wb = Wreg + (size_t)(NL + l) * WBLK;
        else {
            wb = Wreg;
            T(dec_wq + l * M2,  wb + OFF_QK,      512, 512,  0, 0, 1);
            T(dec_wk + l * M2,  wb + OFF_QK + M2, 512, 512,  0, 0, 1);
            T(dec_wv + l * M2,  wb + OFF_WV,      512, 512,  0, 0, 1);
            T(dec_wo + l * M2,  wb + OFF_WO,      512, 512,  0, 0, 1);
            T(dec_cq + l * M2,  wb + OFF_CQ,      512, 512,  0, 0, 1);
            T(dec_ck + l * M2,  wb + OFF_CK,      512, 512,  0, 0, 1);
            T(dec_cv + l * M2,  wb + OFF_CV,      512, 512,  0, 0, 1);
            T(dec_co + l * M2,  wb + OFF_CO,      512, 512,  0, 0, 1);
            T(dec_w1 + l * MF1, wb + OFF_W1,      512, 2048, 0, 0, 1);
            T(dec_w2 + l * MF1, wb + OFF_W2,      2048, 512, 0, 0, 1);
            mgemm<64, 64, 1, 0, 0><<<dim3(8, 32, 1), 256, 0, stream>>>(
                Xb, 512, 0, 0, wb + OFF_CK, 512, 0, 0, Kcr + (size_t)l * MTOK * 512, 512, 0, 0, 512, nullptr);
            mgemm<64, 64, 1, 0, 0><<<dim3(32, 8, 1), 256, 0, stream>>>(
                wb + OFF_CV, 512, 0, 0, Xb, 512, 0, 0, Vtc + (size_t)l * 512 * MTOK, MTOK, 0, 0, 512, nullptr);
        }
        const bool merged0 = full && (l == 0);
        if (!merged0) {
            // masked self-attention (O-proj split-K2 -> Tp4) + LN1 + cross-Q proj
            self_attn(Ybf, wb, trg, 1);
            add_ln_rd<2, 0><<<MTOK, 256, 0, stream>>>(Yb, Tp4, nullptr,
                dec_ln1g + l * DDIM, dec_ln1b + l * DDIM, Ybf);
            mgemm<64, 64, 1, 0, 0><<<dim3(8, 32, 1), 256, 0, stream>>>(
                Ybf, 512, 0, 0, wb + OFF_CQ, 512, 0, 0, QKb, 1024, 0, 0, 512, nullptr);
        }
        // cross-attention (Q from QKb2 for merged layer 0, else QKb)
        const u16* Qsrc = merged0 ? QKb2 : QKb;
        flash_attn<0><<<dim3(8, 32), 256, 0, stream>>>(
            Qsrc, 1024, Kcr + (size_t)l * MTOK * 512, 512, Vtc + (size_t)l * 512 * MTOK, CTX, src);
        o_proj_sk2(CTX, wb + OFF_CO);
        add_ln_rd<2, 0><<<MTOK, 256, 0, stream>>>(Yb, Tp4, nullptr,
            dec_ln2g + l * DDIM, dec_ln2b + l * DDIM, Ybf);
        // FFN
        ffn(Ybf, wb, dec_b1 + l * FFN);
        add_ln_rd<4, 1><<<MTOK, 256, 0, stream>>>(Yb, Tp4, dec_b2 + l * DDIM,
            dec_ln3g + l * DDIM, dec_ln3b + l * DDIM, Ybf);
    }

    // ---- final vocab projection (128x128 tile, XCD-swizzled; 4000 blocks) ----
    mgemm<128, 128, 0, 0, 0, 1><<<dim3(NVOC / 128, MTOK / 128, 1), 256, 0, stream>>>(
        Ybf, 512, 0, 0, projT, 512, 0, 0, OUT, NVOC, 0, 0, 512, nullptr);
}